// Round 2
// baseline (1362.155 us; speedup 1.0000x reference)
//
#include <hip/hip_runtime.h>
#include <cmath>

// ---------------------------------------------------------------------------
// TimestepVisionTransformer — fp32. Round 1: conflict-free decoder convs.
// B=128, IMG=224, P=16, C_IN=1, E=96, H=4, d=24, NAX=14, N=196, M=B*N=25088
// ---------------------------------------------------------------------------

#define B_   128
#define NPATCH 196
#define M_ROWS (B_*NPATCH)     // 25088
#define E_   96

// ---------------------------------------------------------------------------
// time embedding: 1 block x 128 threads
// ---------------------------------------------------------------------------
__global__ void k_time(const float* __restrict__ ts,
                       const float* __restrict__ Wt1, const float* __restrict__ bt1,
                       const float* __restrict__ Wt2, const float* __restrict__ bt2,
                       float* __restrict__ timev)
{
    __shared__ float h[128];
    float e = 0.69314718055994530942f * ts[0];
    float sv = sinf(e), cv = cosf(e);
    int t = threadIdx.x;
    float z = sv * Wt1[t] + cv * Wt1[128 + t] + bt1[t];
    h[t] = z / (1.f + expf(-z));
    __syncthreads();
    if (t < 96) {
        float acc = bt2[t];
        for (int j = 0; j < 128; ++j) acc += h[j] * Wt2[j * 96 + t];
        timev[t] = acc;
    }
}

// ---------------------------------------------------------------------------
// weight repack for all 4 convT layers into per-parity float4 taps.
// Wr[par][ci][o][4] with taps {w[3-ry][3-rx], w[3-ry][1-rx], w[1-ry][3-rx], w[1-ry][1-rx]}
// layer offsets (floats): L1=0 (73728), L2=73728 (18432), L3=92160 (4608), L4=96768 (192)
// ---------------------------------------------------------------------------
__global__ void __launch_bounds__(256) k_repack(const float* __restrict__ w1,
                                                const float* __restrict__ w2,
                                                const float* __restrict__ w3,
                                                const float* __restrict__ w4f,
                                                float* __restrict__ wr)
{
    int i = blockIdx.x * 256 + threadIdx.x;
    const float* src; int CIN, COUT, e; float* dst;
    if      (i < 73728) { src = w1;  CIN = 96; COUT = 48; e = i;          dst = wr; }
    else if (i < 92160) { src = w2;  CIN = 48; COUT = 24; e = i - 73728;  dst = wr + 73728; }
    else if (i < 96768) { src = w3;  CIN = 24; COUT = 12; e = i - 92160;  dst = wr + 92160; }
    else if (i < 96960) { src = w4f; CIN = 12; COUT = 1;  e = i - 96768;  dst = wr + 96768; }
    else return;
    int per = CIN * COUT * 4;
    int par = e / per, rem = e % per;
    int ci = rem / (COUT * 4);
    int o  = (rem >> 2) % COUT;
    int j  = rem & 3;
    int ry = par >> 1, rx = par & 1;
    int wy = (j < 2)  ? (3 - ry) : (1 - ry);
    int wx = (j & 1)  ? (1 - rx) : (3 - rx);
    dst[e] = src[(ci * COUT + o) * 16 + wy * 4 + wx];
}

// ---------------------------------------------------------------------------
// zero the borders of XP1 [128*96 planes][16][16] (interior written by MLP3)
// ---------------------------------------------------------------------------
__global__ void __launch_bounds__(256) k_zb(float* __restrict__ xp)
{
    int idx = blockIdx.x * 256 + threadIdx.x;   // plane*64 + j
    int plane = idx >> 6, j = idx & 63;
    if (plane >= 12288 || j >= 60) return;
    int py, px;
    if      (j < 16) { py = 0;      px = j; }
    else if (j < 32) { py = 15;     px = j - 16; }
    else if (j < 46) { py = j - 31; px = 0; }
    else             { py = j - 45; px = 15; }
    xp[(size_t)plane * 256 + py * 16 + px] = 0.f;
}

// ---------------------------------------------------------------------------
// patch embed GEMM  [25088 x 256] @ WpT[256 x 96]  + bias + RoPE epilogue
// ---------------------------------------------------------------------------
__global__ void __launch_bounds__(256) k_patch(const float* __restrict__ x,
                                               const float* __restrict__ Wp,
                                               const float* __restrict__ bp,
                                               float* __restrict__ out)
{
    __shared__ float As[64][65];
    __shared__ float Ws[64][97];
    int t = threadIdx.x;
    int p0 = blockIdx.x * 64;
    int rg = t >> 4, cg = t & 15;
    float acc[4][6] = {};

    for (int kc = 0; kc < 4; ++kc) {
        __syncthreads();
        for (int idx = t; idx < 64 * 64; idx += 256) {
            int p = idx >> 6, kl = idx & 63;
            int patch = p0 + p;
            int b = patch / NPATCH, n = patch % NPATCH;
            int ny = n / 14, nx = n % 14;
            int py = kc * 4 + (kl >> 4), px = kl & 15;
            As[p][kl] = x[((size_t)b * 224 + ny * 16 + py) * 224 + nx * 16 + px];
        }
        for (int idx = t; idx < 64 * 96; idx += 256) {
            int e = idx >> 6, kl = idx & 63;
            Ws[kl][e] = Wp[e * 256 + kc * 64 + kl];
        }
        __syncthreads();
        for (int kk = 0; kk < 64; ++kk) {
            float a0 = As[rg * 4 + 0][kk];
            float a1 = As[rg * 4 + 1][kk];
            float a2 = As[rg * 4 + 2][kk];
            float a3 = As[rg * 4 + 3][kk];
            const float* wrow = &Ws[kk][cg * 6];
            #pragma unroll
            for (int j = 0; j < 6; ++j) {
                float wv = wrow[j];
                acc[0][j] += a0 * wv; acc[1][j] += a1 * wv;
                acc[2][j] += a2 * wv; acc[3][j] += a3 * wv;
            }
        }
    }
    #pragma unroll
    for (int i = 0; i < 4; ++i) {
        int patch = p0 + rg * 4 + i;
        int n = patch % NPATCH;
        int ny = n / 14, nx = n % 14;
        float yx = (float)(ny + nx);
        #pragma unroll
        for (int j = 0; j < 3; ++j) {
            int e0 = cg * 6 + 2 * j;
            float xe = acc[i][2 * j]     + bp[e0];
            float ye = acc[i][2 * j + 1] + bp[e0 + 1];
            float fi = (float)(e0 >> 1);
            float theta = expf(fi * (-2.f / 96.f) * 9.210340371976184f);
            float ang = theta * yx;
            float c = cosf(ang), s = sinf(ang);
            out[(size_t)patch * 96 + e0]     = xe * c - ye * s;
            out[(size_t)patch * 96 + e0 + 1] = xe * s + ye * c;
        }
    }
}

// ---------------------------------------------------------------------------
// row LayerNorm over 96, wave per row
// ---------------------------------------------------------------------------
__global__ void __launch_bounds__(256) k_ln_row(const float* __restrict__ x,
                                                const float* __restrict__ g,
                                                const float* __restrict__ bv,
                                                float* __restrict__ out, int M)
{
    int lane = threadIdx.x & 63;
    int gw = (blockIdx.x * 256 + threadIdx.x) >> 6;
    int nw = (gridDim.x * 256) >> 6;
    float g0 = g[lane], b0 = bv[lane];
    float g1 = 0.f, b1 = 0.f;
    if (lane < 32) { g1 = g[64 + lane]; b1 = bv[64 + lane]; }
    for (int r = gw; r < M; r += nw) {
        const float* xr = x + (size_t)r * 96;
        float a = xr[lane];
        float c = (lane < 32) ? xr[64 + lane] : 0.f;
        float s = a + c, q = a * a + c * c;
        #pragma unroll
        for (int off = 32; off; off >>= 1) {
            s += __shfl_xor(s, off);
            q += __shfl_xor(q, off);
        }
        float mu = s * (1.f / 96.f);
        float rstd = rsqrtf(q * (1.f / 96.f) - mu * mu + 1e-5f);
        float* orow = out + (size_t)r * 96;
        orow[lane] = (a - mu) * rstd * g0 + b0;
        if (lane < 32) orow[64 + lane] = (c - mu) * rstd * g1 + b1;
    }
}

// ---------------------------------------------------------------------------
// generic row GEMM: A[M,96] @ W[96, NCHUNKS*96] + bias, epilogues
// PADW: write into padded conv-input layout XP1[b][col][16][16] interior
// ---------------------------------------------------------------------------
template<int NCHUNKS, bool SILU, bool RES, bool ADDTIME, bool PADW>
__global__ void __launch_bounds__(256) k_gemm96(const float* __restrict__ A,
                                                const float* __restrict__ W,
                                                const float* __restrict__ bias,
                                                const float* __restrict__ res,
                                                const float* __restrict__ timev,
                                                float* __restrict__ out)
{
    __shared__ float As[64][97];
    __shared__ float Ws[96 * 96];
    constexpr int NTOT = NCHUNKS * 96;
    int t = threadIdx.x;
    size_t row0 = (size_t)blockIdx.x * 64;
    for (int idx = t; idx < 64 * 96; idx += 256)
        As[idx / 96][idx % 96] = A[row0 * 96 + idx];
    int rg = t >> 4, cg = t & 15;
    for (int ch = 0; ch < NCHUNKS; ++ch) {
        __syncthreads();
        for (int idx = t; idx < 96 * 96; idx += 256) {
            int k = idx / 96, c = idx % 96;
            Ws[idx] = W[k * NTOT + ch * 96 + c];
        }
        __syncthreads();
        float acc[4][6] = {};
        for (int kk = 0; kk < 96; ++kk) {
            float a0 = As[rg * 4 + 0][kk];
            float a1 = As[rg * 4 + 1][kk];
            float a2 = As[rg * 4 + 2][kk];
            float a3 = As[rg * 4 + 3][kk];
            const float* wrow = &Ws[kk * 96 + cg * 6];
            #pragma unroll
            for (int j = 0; j < 6; ++j) {
                float wv = wrow[j];
                acc[0][j] += a0 * wv; acc[1][j] += a1 * wv;
                acc[2][j] += a2 * wv; acc[3][j] += a3 * wv;
            }
        }
        #pragma unroll
        for (int i = 0; i < 4; ++i) {
            size_t row = row0 + rg * 4 + i;
            #pragma unroll
            for (int j = 0; j < 6; ++j) {
                int lc = cg * 6 + j;
                int col = ch * 96 + lc;
                float v = acc[i][j] + bias[col];
                if constexpr (RES)     v += res[row * 96 + lc];
                if constexpr (ADDTIME) v += timev[lc];
                if constexpr (SILU)    v = v / (1.f + expf(-v));
                if constexpr (PADW) {
                    size_t b = row / NPATCH; int n = (int)(row % NPATCH);
                    int ny = n / 14, nx = n % 14;
                    out[(b * 96 + col) * 256 + (1 + ny) * 16 + (1 + nx)] = v;
                } else {
                    out[row * NTOT + col] = v;
                }
            }
        }
    }
}

// ---------------------------------------------------------------------------
// attention: grid B*H blocks, 256 threads (4 waves); K,V in LDS (pad 25)
// ---------------------------------------------------------------------------
__global__ void __launch_bounds__(256) k_attn(const float* __restrict__ qkv,
                                              float* __restrict__ o)
{
    int bh = blockIdx.x;
    int b = bh >> 2, h = bh & 3;
    __shared__ float K[196][25];
    __shared__ float V[196][25];
    __shared__ float P[4][200];
    const float* base = qkv + (size_t)b * NPATCH * 288;
    int t = threadIdx.x;
    for (int idx = t; idx < 196 * 24; idx += 256) {
        int n = idx / 24, d = idx % 24;
        K[n][d] = base[n * 288 + 96  + h * 24 + d];
        V[n][d] = base[n * 288 + 192 + h * 24 + d];
    }
    __syncthreads();
    int wave = t >> 6, lane = t & 63;
    const float scale = 0.2041241452319315f;
    for (int q = wave; q < 196; q += 4) {
        float qv[24];
        const float* qrow = base + q * 288 + h * 24;
        #pragma unroll
        for (int d = 0; d < 24; ++d) qv[d] = qrow[d];
        float sc[4];
        float smax = -INFINITY;
        #pragma unroll
        for (int c = 0; c < 4; ++c) {
            int k = c * 64 + lane;
            float s = -INFINITY;
            if (k < 196) {
                float a = 0.f;
                #pragma unroll
                for (int d = 0; d < 24; ++d) a += qv[d] * K[k][d];
                s = a * scale;
            }
            sc[c] = s;
            smax = fmaxf(smax, s);
        }
        #pragma unroll
        for (int off = 32; off; off >>= 1) smax = fmaxf(smax, __shfl_xor(smax, off));
        float sum = 0.f;
        #pragma unroll
        for (int c = 0; c < 4; ++c) {
            int k = c * 64 + lane;
            float e = expf(sc[c] - smax);
            if (k < 196) { P[wave][k] = e; sum += e; }
        }
        #pragma unroll
        for (int off = 32; off; off >>= 1) sum += __shfl_xor(sum, off);
        float inv = 1.f / sum;
        float accv = 0.f;
        if (lane < 48) {
            int dd = lane % 24;
            int k0 = (lane / 24) * 98;
            for (int k = k0; k < k0 + 98; ++k) accv += P[wave][k] * V[k][dd];
        }
        float other = __shfl(accv, lane + 24, 64);
        if (lane < 24)
            o[((size_t)b * NPATCH + q) * 96 + h * 24 + lane] = (accv + other) * inv;
    }
}

// ---------------------------------------------------------------------------
// transposed conv on zero-padded input XP[b][CIN][HIN+2][HIN+2].
// One thread = one (ry, b, pixel-pair): computes outputs (2py+ry, 2px) and
// (2py+ry, 2px+1) for all COUT channels. ry is block-uniform -> weight
// float4 reads are wave-uniform (s_load broadcasts). No LDS.
// grid = 2*B*HIN*HIN/256, block 256.
// ---------------------------------------------------------------------------
template<int CIN, int HIN, int COUT>
__global__ void __launch_bounds__(256) k_convp(const float* __restrict__ xp,
                                               const float* __restrict__ wr,
                                               const float* __restrict__ bias,
                                               float* __restrict__ out)
{
    constexpr int HP = HIN + 2;
    constexpr int HO = 2 * HIN;
    int idx = blockIdx.x * 256 + threadIdx.x;
    int ry = __builtin_amdgcn_readfirstlane(idx / (B_ * HIN * HIN));
    int rem = idx % (B_ * HIN * HIN);
    int b   = rem / (HIN * HIN);
    int pix = rem % (HIN * HIN);
    int py = pix / HIN, px = pix % HIN;
    const float* xb = xp + ((size_t)b * CIN) * (HP * HP) + (py + ry) * HP + px;
    const float4* w4 = (const float4*)wr;
    float acc0[COUT], acc1[COUT];
    #pragma unroll
    for (int o = 0; o < COUT; ++o) { acc0[o] = 0.f; acc1[o] = 0.f; }
    float f00 = xb[0], f01 = xb[1], f02 = xb[2];
    float f10 = xb[HP], f11 = xb[HP + 1], f12 = xb[HP + 2];
    for (int ci = 0; ci < CIN; ++ci) {
        int cn = (ci + 1 < CIN) ? (ci + 1) : (CIN - 1);
        const float* xn = xb + (size_t)cn * (HP * HP);
        float n00 = xn[0], n01 = xn[1], n02 = xn[2];
        float n10 = xn[HP], n11 = xn[HP + 1], n12 = xn[HP + 2];
        const float4* w0 = w4 + ((size_t)(2 * ry) * CIN + ci) * COUT;
        const float4* w1 = w0 + (size_t)CIN * COUT;
        #pragma unroll
        for (int o = 0; o < COUT; ++o) {
            float4 W0 = w0[o], W1 = w1[o];
            acc0[o] += f00 * W0.x + f01 * W0.y + f10 * W0.z + f11 * W0.w;
            acc1[o] += f01 * W1.x + f02 * W1.y + f11 * W1.z + f12 * W1.w;
        }
        f00 = n00; f01 = n01; f02 = n02; f10 = n10; f11 = n11; f12 = n12;
    }
    int oy = 2 * py + ry;
    #pragma unroll
    for (int o = 0; o < COUT; ++o) {
        float bb = bias[o];
        float2 v; v.x = acc0[o] + bb; v.y = acc1[o] + bb;
        *(float2*)(out + ((size_t)(b * COUT + o) * HO + oy) * HO + 2 * px) = v;
    }
}

// ---------------------------------------------------------------------------
// spatial LN (per b,o over H*H) + per-position affine + silu, writing into
// zero-padded layout XP[plane][(H+2)][(H+2)] for the next conv.
// grid = B*COUT planes.
// ---------------------------------------------------------------------------
template<int H>
__global__ void __launch_bounds__(256) k_ln_pad(const float* __restrict__ cin,
                                                const float* __restrict__ g,
                                                const float* __restrict__ bv,
                                                float* __restrict__ xp)
{
    constexpr int HW = H * H;
    constexpr int HP = H + 2;
    constexpr int HWP = HP * HP;
    size_t plane = blockIdx.x;
    const float* src = cin + plane * HW;
    float* dst = xp + plane * HWP;
    int t = threadIdx.x;
    float s = 0.f, q = 0.f;
    for (int i = t; i < HW; i += 256) {
        float v = src[i];
        s += v; q += v * v;
    }
    #pragma unroll
    for (int off = 32; off; off >>= 1) {
        s += __shfl_xor(s, off);
        q += __shfl_xor(q, off);
    }
    __shared__ float rs[8];
    int wave = t >> 6, lane = t & 63;
    if (lane == 0) { rs[wave] = s; rs[4 + wave] = q; }
    __syncthreads();
    float st = rs[0] + rs[1] + rs[2] + rs[3];
    float qt = rs[4] + rs[5] + rs[6] + rs[7];
    float mu = st / (float)HW;
    float rstd = rsqrtf(qt / (float)HW - mu * mu + 1e-5f);
    for (int i = t; i < HWP; i += 256) {
        int py = i / HP, px = i % HP;
        float v = 0.f;
        if (py >= 1 && py <= H && px >= 1 && px <= H) {
            int j = (py - 1) * H + (px - 1);
            float u = (src[j] - mu) * rstd * g[j] + bv[j];
            v = u / (1.f + expf(-u));
        }
        dst[i] = v;
    }
}

// ---------------------------------------------------------------------------
// in-place spatial LN + affine + silu (layer 3; final conv handles bounds)
// ---------------------------------------------------------------------------
template<int HW>
__global__ void __launch_bounds__(256) k_ln_spatial(float* __restrict__ f,
                                                    const float* __restrict__ g,
                                                    const float* __restrict__ bv)
{
    size_t base = (size_t)blockIdx.x * HW;
    int t = threadIdx.x;
    float s = 0.f, q = 0.f;
    for (int i = t; i < HW; i += 256) {
        float v = f[base + i];
        s += v; q += v * v;
    }
    #pragma unroll
    for (int off = 32; off; off >>= 1) {
        s += __shfl_xor(s, off);
        q += __shfl_xor(q, off);
    }
    __shared__ float rs[8];
    int wave = t >> 6, lane = t & 63;
    if (lane == 0) { rs[wave] = s; rs[4 + wave] = q; }
    __syncthreads();
    float st = rs[0] + rs[1] + rs[2] + rs[3];
    float qt = rs[4] + rs[5] + rs[6] + rs[7];
    float mu = st / (float)HW;
    float rstd = rsqrtf(qt / (float)HW - mu * mu + 1e-5f);
    for (int i = t; i < HW; i += 256) {
        float v = (f[base + i] - mu) * rstd * g[i] + bv[i];
        f[base + i] = v / (1.f + expf(-v));
    }
}

// ---------------------------------------------------------------------------
// final convT 12->1 on compact input with boundary masks + silu + clip
// ---------------------------------------------------------------------------
__global__ void __launch_bounds__(256) k_conv_final(const float* __restrict__ x,
                                                    const float* __restrict__ wr,
                                                    const float* __restrict__ bias,
                                                    float* __restrict__ out)
{
    constexpr int HIN = 112, CIN = 12, HP2 = 12544;
    int idx = blockIdx.x * 256 + threadIdx.x;
    int ry = __builtin_amdgcn_readfirstlane(idx / (B_ * HIN * HIN));
    int rem = idx % (B_ * HIN * HIN);
    int b   = rem / (HIN * HIN);
    int pix = rem % (HIN * HIN);
    int py = pix / HIN, px = pix % HIN;
    int r0 = py + ry - 1, r1 = r0 + 1;
    bool my0 = r0 >= 0, my1 = r1 < HIN;
    bool mx0 = px >= 1, mx2 = px + 1 < HIN;
    const float* xb = x + (size_t)b * CIN * HP2;
    const float4* w4 = (const float4*)wr;
    float acc0 = 0.f, acc1 = 0.f;
    #pragma unroll
    for (int ci = 0; ci < CIN; ++ci) {
        const float* xc = xb + ci * HP2;
        const float* xr0 = xc + r0 * HIN + px;
        const float* xr1 = xc + r1 * HIN + px;
        float g00 = (my0 && mx0) ? xr0[-1] : 0.f;
        float g01 = my0 ? xr0[0] : 0.f;
        float g02 = (my0 && mx2) ? xr0[1] : 0.f;
        float g10 = (my1 && mx0) ? xr1[-1] : 0.f;
        float g11 = my1 ? xr1[0] : 0.f;
        float g12 = (my1 && mx2) ? xr1[1] : 0.f;
        float4 W0 = w4[(2 * ry) * CIN + ci];
        float4 W1 = w4[(2 * ry + 1) * CIN + ci];
        acc0 += g00 * W0.x + g01 * W0.y + g10 * W0.z + g11 * W0.w;
        acc1 += g01 * W1.x + g02 * W1.y + g11 * W1.z + g12 * W1.w;
    }
    float bb = bias[0];
    float u0 = acc0 + bb, u1 = acc1 + bb;
    u0 = u0 / (1.f + expf(-u0));
    u1 = u1 / (1.f + expf(-u1));
    float2 v;
    v.x = fminf(fmaxf(u0, 0.f), 1.f);
    v.y = fminf(fmaxf(u1, 0.f), 1.f);
    int oy = 2 * py + ry;
    *(float2*)(out + (size_t)b * 50176 + oy * 224 + 2 * px) = v;
}

// ---------------------------------------------------------------------------
// launch
// ---------------------------------------------------------------------------
extern "C" void kernel_launch(void* const* d_in, const int* in_sizes, int n_in,
                              void* d_out, int out_size, void* d_ws, size_t ws_size,
                              hipStream_t stream)
{
    const float* x       = (const float*)d_in[0];
    const float* ts      = (const float*)d_in[1];
    const float* Wp      = (const float*)d_in[2];
    const float* bp      = (const float*)d_in[3];
    const float* Wt1     = (const float*)d_in[4];
    const float* bt1     = (const float*)d_in[5];
    const float* Wt2     = (const float*)d_in[6];
    const float* bt2     = (const float*)d_in[7];
    const float* a0_g    = (const float*)d_in[8];
    const float* a0_b    = (const float*)d_in[9];
    const float* a0_Wqkv = (const float*)d_in[10];
    const float* a0_bqkv = (const float*)d_in[11];
    const float* a0_Wo   = (const float*)d_in[12];
    const float* a0_bo   = (const float*)d_in[13];
    const float* a1_g    = (const float*)d_in[14];
    const float* a1_b    = (const float*)d_in[15];
    const float* a1_Wqkv = (const float*)d_in[16];
    const float* a1_bqkv = (const float*)d_in[17];
    const float* a1_Wo   = (const float*)d_in[18];
    const float* a1_bo   = (const float*)d_in[19];
    const float* Wm0     = (const float*)d_in[20];
    const float* bm0     = (const float*)d_in[21];
    const float* Wm1     = (const float*)d_in[22];
    const float* bm1     = (const float*)d_in[23];
    const float* Wm2     = (const float*)d_in[24];
    const float* bm2     = (const float*)d_in[25];
    const float* Wd1     = (const float*)d_in[26];
    const float* bd1     = (const float*)d_in[27];
    const float* l1g     = (const float*)d_in[28];
    const float* l1b     = (const float*)d_in[29];
    const float* Wd2     = (const float*)d_in[30];
    const float* bd2     = (const float*)d_in[31];
    const float* l2g     = (const float*)d_in[32];
    const float* l2b     = (const float*)d_in[33];
    const float* Wd3     = (const float*)d_in[34];
    const float* bd3     = (const float*)d_in[35];
    const float* l3g     = (const float*)d_in[36];
    const float* l3b     = (const float*)d_in[37];
    const float* Wd4     = (const float*)d_in[38];
    const float* bd4     = (const float*)d_in[39];
    float* out = (float*)d_out;

    // arena (floats); R = 25088*96
    const size_t R = 2408448;
    float* ws   = (float*)d_ws;
    float* tvec = ws;                          // 96
    float* p0   = ws + 512;                    // R
    float* h    = ws + 512 + R;                // R
    float* qkvb = ws + 512 + 2 * R;            // 3R
    float* ob   = ws + 512 + 5 * R;            // R
    float* p1   = ws + 512 + 6 * R;            // R
    // decoder aliases:
    float* XP1  = ws + 512 + 2 * R;            // 3,145,728  (qkv region)
    float* C1   = ws + 512 + 5 * R;            // 4,816,896  (ob+p1 regions)
    float* XP2  = ws + 512 + 7 * R;            // 5,529,600
    float* C2   = ws + 512;                    // 9,633,792  (p0..qkv regions)
    float* XP3  = ws + 512 + 7 * R + 5529600;  // 10,334,208
    float* C3   = ws + 512;                    // 19,267,584 (p0..XP2 regions)
    float* Wr   = ws + 512 + 7 * R + 5529600 + 10334208;  // 96,960
    const size_t NEED = (512 + 7 * R + 5529600 + 10334208 + 96960) * sizeof(float); // ~131.3 MB
    if (ws_size < NEED) return;

    k_time<<<1, 128, 0, stream>>>(ts, Wt1, bt1, Wt2, bt2, tvec);
    k_repack<<<379, 256, 0, stream>>>(Wd1, Wd2, Wd3, Wd4, Wr);
    k_patch<<<M_ROWS / 64, 256, 0, stream>>>(x, Wp, bp, p0);

    // MHSA block 0
    k_ln_row<<<1024, 256, 0, stream>>>(p0, a0_g, a0_b, h, M_ROWS);
    k_gemm96<3, false, false, false, false><<<M_ROWS / 64, 256, 0, stream>>>(
        h, a0_Wqkv, a0_bqkv, nullptr, nullptr, qkvb);
    k_attn<<<B_ * 4, 256, 0, stream>>>(qkvb, ob);
    k_gemm96<1, false, true, false, false><<<M_ROWS / 64, 256, 0, stream>>>(
        ob, a0_Wo, a0_bo, p0, nullptr, p1);

    // MHSA block 1 (+time in epilogue)
    k_ln_row<<<1024, 256, 0, stream>>>(p1, a1_g, a1_b, h, M_ROWS);
    k_gemm96<3, false, false, false, false><<<M_ROWS / 64, 256, 0, stream>>>(
        h, a1_Wqkv, a1_bqkv, nullptr, nullptr, qkvb);
    k_attn<<<B_ * 4, 256, 0, stream>>>(qkvb, ob);
    k_gemm96<1, false, true, true, false><<<M_ROWS / 64, 256, 0, stream>>>(
        ob, a1_Wo, a1_bo, p1, tvec, p0);

    // qkv region is now free: zero XP1 borders before MLP3 writes interior
    k_zb<<<3072, 256, 0, stream>>>(XP1);

    // MLP x3 (silu); last writes padded XP1[b][e][16][16]
    k_gemm96<1, true, false, false, false><<<M_ROWS / 64, 256, 0, stream>>>(
        p0, Wm0, bm0, nullptr, nullptr, p1);
    k_gemm96<1, true, false, false, false><<<M_ROWS / 64, 256, 0, stream>>>(
        p1, Wm1, bm1, nullptr, nullptr, p0);
    k_gemm96<1, true, false, false, true><<<M_ROWS / 64, 256, 0, stream>>>(
        p0, Wm2, bm2, nullptr, nullptr, XP1);

    // decoder
    k_convp<96, 14, 48><<<196, 256, 0, stream>>>(XP1, Wr, bd1, C1);
    k_ln_pad<28><<<B_ * 48, 256, 0, stream>>>(C1, l1g, l1b, XP2);
    k_convp<48, 28, 24><<<784, 256, 0, stream>>>(XP2, Wr + 73728, bd2, C2);
    k_ln_pad<56><<<B_ * 24, 256, 0, stream>>>(C2, l2g, l2b, XP3);
    k_convp<24, 56, 12><<<3136, 256, 0, stream>>>(XP3, Wr + 92160, bd3, C3);
    k_ln_spatial<12544><<<B_ * 12, 256, 0, stream>>>(C3, l3g, l3b);
    k_conv_final<<<12544, 256, 0, stream>>>(C3, Wr + 96768, bd4, out);
}

// Round 3
// 933.308 us; speedup vs baseline: 1.4595x; 1.4595x over previous
//
#include <hip/hip_runtime.h>
#include <cmath>

// ---------------------------------------------------------------------------
// TimestepVisionTransformer — fp32. Round 2: conv channel-group split
// (fix occupancy + register pressure of decoder convs).
// B=128, IMG=224, P=16, C_IN=1, E=96, H=4, d=24, NAX=14, N=196, M=B*N=25088
// ---------------------------------------------------------------------------

#define B_   128
#define NPATCH 196
#define M_ROWS (B_*NPATCH)     // 25088
#define E_   96

// ---------------------------------------------------------------------------
// time embedding: 1 block x 128 threads
// ---------------------------------------------------------------------------
__global__ void k_time(const float* __restrict__ ts,
                       const float* __restrict__ Wt1, const float* __restrict__ bt1,
                       const float* __restrict__ Wt2, const float* __restrict__ bt2,
                       float* __restrict__ timev)
{
    __shared__ float h[128];
    float e = 0.69314718055994530942f * ts[0];
    float sv = sinf(e), cv = cosf(e);
    int t = threadIdx.x;
    float z = sv * Wt1[t] + cv * Wt1[128 + t] + bt1[t];
    h[t] = z / (1.f + expf(-z));
    __syncthreads();
    if (t < 96) {
        float acc = bt2[t];
        for (int j = 0; j < 128; ++j) acc += h[j] * Wt2[j * 96 + t];
        timev[t] = acc;
    }
}

// ---------------------------------------------------------------------------
// weight repack for all 4 convT layers into per-parity float4 taps.
// Wr[par][ci][o][4] with taps {w[3-ry][3-rx], w[3-ry][1-rx], w[1-ry][3-rx], w[1-ry][1-rx]}
// layer offsets (floats): L1=0 (73728), L2=73728 (18432), L3=92160 (4608), L4=96768 (192)
// ---------------------------------------------------------------------------
__global__ void __launch_bounds__(256) k_repack(const float* __restrict__ w1,
                                                const float* __restrict__ w2,
                                                const float* __restrict__ w3,
                                                const float* __restrict__ w4f,
                                                float* __restrict__ wr)
{
    int i = blockIdx.x * 256 + threadIdx.x;
    const float* src; int CIN, COUT, e; float* dst;
    if      (i < 73728) { src = w1;  CIN = 96; COUT = 48; e = i;          dst = wr; }
    else if (i < 92160) { src = w2;  CIN = 48; COUT = 24; e = i - 73728;  dst = wr + 73728; }
    else if (i < 96768) { src = w3;  CIN = 24; COUT = 12; e = i - 92160;  dst = wr + 92160; }
    else if (i < 96960) { src = w4f; CIN = 12; COUT = 1;  e = i - 96768;  dst = wr + 96768; }
    else return;
    int per = CIN * COUT * 4;
    int par = e / per, rem = e % per;
    int ci = rem / (COUT * 4);
    int o  = (rem >> 2) % COUT;
    int j  = rem & 3;
    int ry = par >> 1, rx = par & 1;
    int wy = (j < 2)  ? (3 - ry) : (1 - ry);
    int wx = (j & 1)  ? (1 - rx) : (3 - rx);
    dst[e] = src[(ci * COUT + o) * 16 + wy * 4 + wx];
}

// ---------------------------------------------------------------------------
// zero the borders of XP1 [128*96 planes][16][16] (interior written by MLP3)
// ---------------------------------------------------------------------------
__global__ void __launch_bounds__(256) k_zb(float* __restrict__ xp)
{
    int idx = blockIdx.x * 256 + threadIdx.x;   // plane*64 + j
    int plane = idx >> 6, j = idx & 63;
    if (plane >= 12288 || j >= 60) return;
    int py, px;
    if      (j < 16) { py = 0;      px = j; }
    else if (j < 32) { py = 15;     px = j - 16; }
    else if (j < 46) { py = j - 31; px = 0; }
    else             { py = j - 45; px = 15; }
    xp[(size_t)plane * 256 + py * 16 + px] = 0.f;
}

// ---------------------------------------------------------------------------
// patch embed GEMM  [25088 x 256] @ WpT[256 x 96]  + bias + RoPE epilogue
// ---------------------------------------------------------------------------
__global__ void __launch_bounds__(256) k_patch(const float* __restrict__ x,
                                               const float* __restrict__ Wp,
                                               const float* __restrict__ bp,
                                               float* __restrict__ out)
{
    __shared__ float As[64][65];
    __shared__ float Ws[64][97];
    int t = threadIdx.x;
    int p0 = blockIdx.x * 64;
    int rg = t >> 4, cg = t & 15;
    float acc[4][6] = {};

    for (int kc = 0; kc < 4; ++kc) {
        __syncthreads();
        for (int idx = t; idx < 64 * 64; idx += 256) {
            int p = idx >> 6, kl = idx & 63;
            int patch = p0 + p;
            int b = patch / NPATCH, n = patch % NPATCH;
            int ny = n / 14, nx = n % 14;
            int py = kc * 4 + (kl >> 4), px = kl & 15;
            As[p][kl] = x[((size_t)b * 224 + ny * 16 + py) * 224 + nx * 16 + px];
        }
        for (int idx = t; idx < 64 * 96; idx += 256) {
            int e = idx >> 6, kl = idx & 63;
            Ws[kl][e] = Wp[e * 256 + kc * 64 + kl];
        }
        __syncthreads();
        for (int kk = 0; kk < 64; ++kk) {
            float a0 = As[rg * 4 + 0][kk];
            float a1 = As[rg * 4 + 1][kk];
            float a2 = As[rg * 4 + 2][kk];
            float a3 = As[rg * 4 + 3][kk];
            const float* wrow = &Ws[kk][cg * 6];
            #pragma unroll
            for (int j = 0; j < 6; ++j) {
                float wv = wrow[j];
                acc[0][j] += a0 * wv; acc[1][j] += a1 * wv;
                acc[2][j] += a2 * wv; acc[3][j] += a3 * wv;
            }
        }
    }
    #pragma unroll
    for (int i = 0; i < 4; ++i) {
        int patch = p0 + rg * 4 + i;
        int n = patch % NPATCH;
        int ny = n / 14, nx = n % 14;
        float yx = (float)(ny + nx);
        #pragma unroll
        for (int j = 0; j < 3; ++j) {
            int e0 = cg * 6 + 2 * j;
            float xe = acc[i][2 * j]     + bp[e0];
            float ye = acc[i][2 * j + 1] + bp[e0 + 1];
            float fi = (float)(e0 >> 1);
            float theta = expf(fi * (-2.f / 96.f) * 9.210340371976184f);
            float ang = theta * yx;
            float c = cosf(ang), s = sinf(ang);
            out[(size_t)patch * 96 + e0]     = xe * c - ye * s;
            out[(size_t)patch * 96 + e0 + 1] = xe * s + ye * c;
        }
    }
}

// ---------------------------------------------------------------------------
// row LayerNorm over 96, wave per row
// ---------------------------------------------------------------------------
__global__ void __launch_bounds__(256) k_ln_row(const float* __restrict__ x,
                                                const float* __restrict__ g,
                                                const float* __restrict__ bv,
                                                float* __restrict__ out, int M)
{
    int lane = threadIdx.x & 63;
    int gw = (blockIdx.x * 256 + threadIdx.x) >> 6;
    int nw = (gridDim.x * 256) >> 6;
    float g0 = g[lane], b0 = bv[lane];
    float g1 = 0.f, b1 = 0.f;
    if (lane < 32) { g1 = g[64 + lane]; b1 = bv[64 + lane]; }
    for (int r = gw; r < M; r += nw) {
        const float* xr = x + (size_t)r * 96;
        float a = xr[lane];
        float c = (lane < 32) ? xr[64 + lane] : 0.f;
        float s = a + c, q = a * a + c * c;
        #pragma unroll
        for (int off = 32; off; off >>= 1) {
            s += __shfl_xor(s, off);
            q += __shfl_xor(q, off);
        }
        float mu = s * (1.f / 96.f);
        float rstd = rsqrtf(q * (1.f / 96.f) - mu * mu + 1e-5f);
        float* orow = out + (size_t)r * 96;
        orow[lane] = (a - mu) * rstd * g0 + b0;
        if (lane < 32) orow[64 + lane] = (c - mu) * rstd * g1 + b1;
    }
}

// ---------------------------------------------------------------------------
// generic row GEMM: A[M,96] @ W[96, NCHUNKS*96] + bias, epilogues
// PADW: write into padded conv-input layout XP1[b][col][16][16] interior
// ---------------------------------------------------------------------------
template<int NCHUNKS, bool SILU, bool RES, bool ADDTIME, bool PADW>
__global__ void __launch_bounds__(256) k_gemm96(const float* __restrict__ A,
                                                const float* __restrict__ W,
                                                const float* __restrict__ bias,
                                                const float* __restrict__ res,
                                                const float* __restrict__ timev,
                                                float* __restrict__ out)
{
    __shared__ float As[64][97];
    __shared__ float Ws[96 * 96];
    constexpr int NTOT = NCHUNKS * 96;
    int t = threadIdx.x;
    size_t row0 = (size_t)blockIdx.x * 64;
    for (int idx = t; idx < 64 * 96; idx += 256)
        As[idx / 96][idx % 96] = A[row0 * 96 + idx];
    int rg = t >> 4, cg = t & 15;
    for (int ch = 0; ch < NCHUNKS; ++ch) {
        __syncthreads();
        for (int idx = t; idx < 96 * 96; idx += 256) {
            int k = idx / 96, c = idx % 96;
            Ws[idx] = W[k * NTOT + ch * 96 + c];
        }
        __syncthreads();
        float acc[4][6] = {};
        for (int kk = 0; kk < 96; ++kk) {
            float a0 = As[rg * 4 + 0][kk];
            float a1 = As[rg * 4 + 1][kk];
            float a2 = As[rg * 4 + 2][kk];
            float a3 = As[rg * 4 + 3][kk];
            const float* wrow = &Ws[kk * 96 + cg * 6];
            #pragma unroll
            for (int j = 0; j < 6; ++j) {
                float wv = wrow[j];
                acc[0][j] += a0 * wv; acc[1][j] += a1 * wv;
                acc[2][j] += a2 * wv; acc[3][j] += a3 * wv;
            }
        }
        #pragma unroll
        for (int i = 0; i < 4; ++i) {
            size_t row = row0 + rg * 4 + i;
            #pragma unroll
            for (int j = 0; j < 6; ++j) {
                int lc = cg * 6 + j;
                int col = ch * 96 + lc;
                float v = acc[i][j] + bias[col];
                if constexpr (RES)     v += res[row * 96 + lc];
                if constexpr (ADDTIME) v += timev[lc];
                if constexpr (SILU)    v = v / (1.f + expf(-v));
                if constexpr (PADW) {
                    size_t b = row / NPATCH; int n = (int)(row % NPATCH);
                    int ny = n / 14, nx = n % 14;
                    out[(b * 96 + col) * 256 + (1 + ny) * 16 + (1 + nx)] = v;
                } else {
                    out[row * NTOT + col] = v;
                }
            }
        }
    }
}

// ---------------------------------------------------------------------------
// attention: grid B*H blocks, 256 threads (4 waves); K,V in LDS (pad 25)
// ---------------------------------------------------------------------------
__global__ void __launch_bounds__(256) k_attn(const float* __restrict__ qkv,
                                              float* __restrict__ o)
{
    int bh = blockIdx.x;
    int b = bh >> 2, h = bh & 3;
    __shared__ float K[196][25];
    __shared__ float V[196][25];
    __shared__ float P[4][200];
    const float* base = qkv + (size_t)b * NPATCH * 288;
    int t = threadIdx.x;
    for (int idx = t; idx < 196 * 24; idx += 256) {
        int n = idx / 24, d = idx % 24;
        K[n][d] = base[n * 288 + 96  + h * 24 + d];
        V[n][d] = base[n * 288 + 192 + h * 24 + d];
    }
    __syncthreads();
    int wave = t >> 6, lane = t & 63;
    const float scale = 0.2041241452319315f;
    for (int q = wave; q < 196; q += 4) {
        float qv[24];
        const float* qrow = base + q * 288 + h * 24;
        #pragma unroll
        for (int d = 0; d < 24; ++d) qv[d] = qrow[d];
        float sc[4];
        float smax = -INFINITY;
        #pragma unroll
        for (int c = 0; c < 4; ++c) {
            int k = c * 64 + lane;
            float s = -INFINITY;
            if (k < 196) {
                float a = 0.f;
                #pragma unroll
                for (int d = 0; d < 24; ++d) a += qv[d] * K[k][d];
                s = a * scale;
            }
            sc[c] = s;
            smax = fmaxf(smax, s);
        }
        #pragma unroll
        for (int off = 32; off; off >>= 1) smax = fmaxf(smax, __shfl_xor(smax, off));
        float sum = 0.f;
        #pragma unroll
        for (int c = 0; c < 4; ++c) {
            int k = c * 64 + lane;
            float e = expf(sc[c] - smax);
            if (k < 196) { P[wave][k] = e; sum += e; }
        }
        #pragma unroll
        for (int off = 32; off; off >>= 1) sum += __shfl_xor(sum, off);
        float inv = 1.f / sum;
        float accv = 0.f;
        if (lane < 48) {
            int dd = lane % 24;
            int k0 = (lane / 24) * 98;
            for (int k = k0; k < k0 + 98; ++k) accv += P[wave][k] * V[k][dd];
        }
        float other = __shfl(accv, lane + 24, 64);
        if (lane < 24)
            o[((size_t)b * NPATCH + q) * 96 + h * 24 + lane] = (accv + other) * inv;
    }
}

// ---------------------------------------------------------------------------
// transposed conv on zero-padded input XP[b][CIN][HIN+2][HIN+2].
// Channel-group split: one thread = (ry, og, b, pixel-pair), computing
// outputs (2py+ry, 2px..2px+1) for G channels. ry/og derived from blockIdx
// (scalar) -> weight float4 reads are s_load broadcasts. No LDS.
// grid = 2 * (COUT/G) * B*HIN*HIN/256.
// ---------------------------------------------------------------------------
template<int CIN, int HIN, int COUT, int G>
__global__ void __launch_bounds__(256) k_convg(const float* __restrict__ xp,
                                               const float* __restrict__ wr,
                                               const float* __restrict__ bias,
                                               float* __restrict__ out)
{
    constexpr int HP = HIN + 2;
    constexpr int HO = 2 * HIN;
    constexpr int NPB = (B_ * HIN * HIN) / 256;   // pixel-blocks per (ry,og)
    int pb = blockIdx.x % NPB;
    int z  = blockIdx.x / NPB;        // z = ry * (COUT/G) + og
    int og = z % (COUT / G);
    int ry = z / (COUT / G);
    int o0 = og * G;
    int rem = pb * 256 + threadIdx.x; // in [0, B*HIN*HIN)
    int b   = rem / (HIN * HIN);
    int pix = rem % (HIN * HIN);
    int py = pix / HIN, px = pix % HIN;
    const float* xb = xp + ((size_t)b * CIN) * (HP * HP) + (py + ry) * HP + px;
    const float4* w4 = (const float4*)wr;
    float acc0[G], acc1[G];
    #pragma unroll
    for (int o = 0; o < G; ++o) { acc0[o] = 0.f; acc1[o] = 0.f; }
    float f00 = xb[0], f01 = xb[1], f02 = xb[2];
    float f10 = xb[HP], f11 = xb[HP + 1], f12 = xb[HP + 2];
    for (int ci = 0; ci < CIN; ++ci) {
        int cn = (ci + 1 < CIN) ? (ci + 1) : (CIN - 1);
        const float* xn = xb + (size_t)cn * (HP * HP);
        float n00 = xn[0], n01 = xn[1], n02 = xn[2];
        float n10 = xn[HP], n11 = xn[HP + 1], n12 = xn[HP + 2];
        const float4* w0 = w4 + ((size_t)(2 * ry) * CIN + ci) * COUT + o0;
        const float4* w1 = w0 + (size_t)CIN * COUT;
        #pragma unroll
        for (int o = 0; o < G; ++o) {
            float4 W0 = w0[o], W1 = w1[o];
            acc0[o] += f00 * W0.x + f01 * W0.y + f10 * W0.z + f11 * W0.w;
            acc1[o] += f01 * W1.x + f02 * W1.y + f11 * W1.z + f12 * W1.w;
        }
        f00 = n00; f01 = n01; f02 = n02; f10 = n10; f11 = n11; f12 = n12;
    }
    int oy = 2 * py + ry;
    #pragma unroll
    for (int o = 0; o < G; ++o) {
        float bb = bias[o0 + o];
        float2 v; v.x = acc0[o] + bb; v.y = acc1[o] + bb;
        *(float2*)(out + ((size_t)(b * COUT + o0 + o) * HO + oy) * HO + 2 * px) = v;
    }
}

// ---------------------------------------------------------------------------
// spatial LN (per b,o over H*H) + per-position affine + silu, writing into
// zero-padded layout XP[plane][(H+2)][(H+2)] for the next conv.
// ---------------------------------------------------------------------------
template<int H>
__global__ void __launch_bounds__(256) k_ln_pad(const float* __restrict__ cin,
                                                const float* __restrict__ g,
                                                const float* __restrict__ bv,
                                                float* __restrict__ xp)
{
    constexpr int HW = H * H;
    constexpr int HP = H + 2;
    constexpr int HWP = HP * HP;
    size_t plane = blockIdx.x;
    const float* src = cin + plane * HW;
    float* dst = xp + plane * HWP;
    int t = threadIdx.x;
    float s = 0.f, q = 0.f;
    for (int i = t; i < HW; i += 256) {
        float v = src[i];
        s += v; q += v * v;
    }
    #pragma unroll
    for (int off = 32; off; off >>= 1) {
        s += __shfl_xor(s, off);
        q += __shfl_xor(q, off);
    }
    __shared__ float rs[8];
    int wave = t >> 6, lane = t & 63;
    if (lane == 0) { rs[wave] = s; rs[4 + wave] = q; }
    __syncthreads();
    float st = rs[0] + rs[1] + rs[2] + rs[3];
    float qt = rs[4] + rs[5] + rs[6] + rs[7];
    float mu = st / (float)HW;
    float rstd = rsqrtf(qt / (float)HW - mu * mu + 1e-5f);
    for (int i = t; i < HWP; i += 256) {
        int py = i / HP, px = i % HP;
        float v = 0.f;
        if (py >= 1 && py <= H && px >= 1 && px <= H) {
            int j = (py - 1) * H + (px - 1);
            float u = (src[j] - mu) * rstd * g[j] + bv[j];
            v = u / (1.f + expf(-u));
        }
        dst[i] = v;
    }
}

// ---------------------------------------------------------------------------
// in-place spatial LN + affine + silu (layer 3; final conv handles bounds)
// ---------------------------------------------------------------------------
template<int HW>
__global__ void __launch_bounds__(256) k_ln_spatial(float* __restrict__ f,
                                                    const float* __restrict__ g,
                                                    const float* __restrict__ bv)
{
    size_t base = (size_t)blockIdx.x * HW;
    int t = threadIdx.x;
    float s = 0.f, q = 0.f;
    for (int i = t; i < HW; i += 256) {
        float v = f[base + i];
        s += v; q += v * v;
    }
    #pragma unroll
    for (int off = 32; off; off >>= 1) {
        s += __shfl_xor(s, off);
        q += __shfl_xor(q, off);
    }
    __shared__ float rs[8];
    int wave = t >> 6, lane = t & 63;
    if (lane == 0) { rs[wave] = s; rs[4 + wave] = q; }
    __syncthreads();
    float st = rs[0] + rs[1] + rs[2] + rs[3];
    float qt = rs[4] + rs[5] + rs[6] + rs[7];
    float mu = st / (float)HW;
    float rstd = rsqrtf(qt / (float)HW - mu * mu + 1e-5f);
    for (int i = t; i < HW; i += 256) {
        float v = (f[base + i] - mu) * rstd * g[i] + bv[i];
        f[base + i] = v / (1.f + expf(-v));
    }
}

// ---------------------------------------------------------------------------
// final convT 12->1 on compact input with boundary masks + silu + clip
// ---------------------------------------------------------------------------
__global__ void __launch_bounds__(256) k_conv_final(const float* __restrict__ x,
                                                    const float* __restrict__ wr,
                                                    const float* __restrict__ bias,
                                                    float* __restrict__ out)
{
    constexpr int HIN = 112, CIN = 12, HP2 = 12544;
    constexpr int NPB = (B_ * HIN * HIN) / 256;   // 6272
    int pb = blockIdx.x % NPB;
    int ry = blockIdx.x / NPB;
    int rem = pb * 256 + threadIdx.x;
    int b   = rem / (HIN * HIN);
    int pix = rem % (HIN * HIN);
    int py = pix / HIN, px = pix % HIN;
    int r0 = py + ry - 1, r1 = r0 + 1;
    bool my0 = r0 >= 0, my1 = r1 < HIN;
    bool mx0 = px >= 1, mx2 = px + 1 < HIN;
    const float* xb = x + (size_t)b * CIN * HP2;
    const float4* w4 = (const float4*)wr;
    float acc0 = 0.f, acc1 = 0.f;
    #pragma unroll
    for (int ci = 0; ci < CIN; ++ci) {
        const float* xc = xb + ci * HP2;
        const float* xr0 = xc + r0 * HIN + px;
        const float* xr1 = xc + r1 * HIN + px;
        float g00 = (my0 && mx0) ? xr0[-1] : 0.f;
        float g01 = my0 ? xr0[0] : 0.f;
        float g02 = (my0 && mx2) ? xr0[1] : 0.f;
        float g10 = (my1 && mx0) ? xr1[-1] : 0.f;
        float g11 = my1 ? xr1[0] : 0.f;
        float g12 = (my1 && mx2) ? xr1[1] : 0.f;
        float4 W0 = w4[(2 * ry) * CIN + ci];
        float4 W1 = w4[(2 * ry + 1) * CIN + ci];
        acc0 += g00 * W0.x + g01 * W0.y + g10 * W0.z + g11 * W0.w;
        acc1 += g01 * W1.x + g02 * W1.y + g11 * W1.z + g12 * W1.w;
    }
    float bb = bias[0];
    float u0 = acc0 + bb, u1 = acc1 + bb;
    u0 = u0 / (1.f + expf(-u0));
    u1 = u1 / (1.f + expf(-u1));
    float2 v;
    v.x = fminf(fmaxf(u0, 0.f), 1.f);
    v.y = fminf(fmaxf(u1, 0.f), 1.f);
    int oy = 2 * py + ry;
    *(float2*)(out + (size_t)b * 50176 + oy * 224 + 2 * px) = v;
}

// ---------------------------------------------------------------------------
// launch
// ---------------------------------------------------------------------------
extern "C" void kernel_launch(void* const* d_in, const int* in_sizes, int n_in,
                              void* d_out, int out_size, void* d_ws, size_t ws_size,
                              hipStream_t stream)
{
    const float* x       = (const float*)d_in[0];
    const float* ts      = (const float*)d_in[1];
    const float* Wp      = (const float*)d_in[2];
    const float* bp      = (const float*)d_in[3];
    const float* Wt1     = (const float*)d_in[4];
    const float* bt1     = (const float*)d_in[5];
    const float* Wt2     = (const float*)d_in[6];
    const float* bt2     = (const float*)d_in[7];
    const float* a0_g    = (const float*)d_in[8];
    const float* a0_b    = (const float*)d_in[9];
    const float* a0_Wqkv = (const float*)d_in[10];
    const float* a0_bqkv = (const float*)d_in[11];
    const float* a0_Wo   = (const float*)d_in[12];
    const float* a0_bo   = (const float*)d_in[13];
    const float* a1_g    = (const float*)d_in[14];
    const float* a1_b    = (const float*)d_in[15];
    const float* a1_Wqkv = (const float*)d_in[16];
    const float* a1_bqkv = (const float*)d_in[17];
    const float* a1_Wo   = (const float*)d_in[18];
    const float* a1_bo   = (const float*)d_in[19];
    const float* Wm0     = (const float*)d_in[20];
    const float* bm0     = (const float*)d_in[21];
    const float* Wm1     = (const float*)d_in[22];
    const float* bm1     = (const float*)d_in[23];
    const float* Wm2     = (const float*)d_in[24];
    const float* bm2     = (const float*)d_in[25];
    const float* Wd1     = (const float*)d_in[26];
    const float* bd1     = (const float*)d_in[27];
    const float* l1g     = (const float*)d_in[28];
    const float* l1b     = (const float*)d_in[29];
    const float* Wd2     = (const float*)d_in[30];
    const float* bd2     = (const float*)d_in[31];
    const float* l2g     = (const float*)d_in[32];
    const float* l2b     = (const float*)d_in[33];
    const float* Wd3     = (const float*)d_in[34];
    const float* bd3     = (const float*)d_in[35];
    const float* l3g     = (const float*)d_in[36];
    const float* l3b     = (const float*)d_in[37];
    const float* Wd4     = (const float*)d_in[38];
    const float* bd4     = (const float*)d_in[39];
    float* out = (float*)d_out;

    // arena (floats); R = 25088*96
    const size_t R = 2408448;
    float* ws   = (float*)d_ws;
    float* tvec = ws;                          // 96
    float* p0   = ws + 512;                    // R
    float* h    = ws + 512 + R;                // R
    float* qkvb = ws + 512 + 2 * R;            // 3R
    float* ob   = ws + 512 + 5 * R;            // R
    float* p1   = ws + 512 + 6 * R;            // R
    // decoder aliases:
    float* XP1  = ws + 512 + 2 * R;            // 3,145,728  (qkv region)
    float* C1   = ws + 512 + 5 * R;            // 4,816,896  (ob+p1 regions)
    float* XP2  = ws + 512 + 7 * R;            // 5,529,600
    float* C2   = ws + 512;                    // 9,633,792  (p0..qkv regions)
    float* XP3  = ws + 512 + 7 * R + 5529600;  // 10,334,208
    float* C3   = ws + 512;                    // 19,267,584 (p0..XP2 regions)
    float* Wr   = ws + 512 + 7 * R + 5529600 + 10334208;  // 96,960
    const size_t NEED = (512 + 7 * R + 5529600 + 10334208 + 96960) * sizeof(float); // ~131.3 MB
    if (ws_size < NEED) return;

    k_time<<<1, 128, 0, stream>>>(ts, Wt1, bt1, Wt2, bt2, tvec);
    k_repack<<<379, 256, 0, stream>>>(Wd1, Wd2, Wd3, Wd4, Wr);
    k_patch<<<M_ROWS / 64, 256, 0, stream>>>(x, Wp, bp, p0);

    // MHSA block 0
    k_ln_row<<<1024, 256, 0, stream>>>(p0, a0_g, a0_b, h, M_ROWS);
    k_gemm96<3, false, false, false, false><<<M_ROWS / 64, 256, 0, stream>>>(
        h, a0_Wqkv, a0_bqkv, nullptr, nullptr, qkvb);
    k_attn<<<B_ * 4, 256, 0, stream>>>(qkvb, ob);
    k_gemm96<1, false, true, false, false><<<M_ROWS / 64, 256, 0, stream>>>(
        ob, a0_Wo, a0_bo, p0, nullptr, p1);

    // MHSA block 1 (+time in epilogue)
    k_ln_row<<<1024, 256, 0, stream>>>(p1, a1_g, a1_b, h, M_ROWS);
    k_gemm96<3, false, false, false, false><<<M_ROWS / 64, 256, 0, stream>>>(
        h, a1_Wqkv, a1_bqkv, nullptr, nullptr, qkvb);
    k_attn<<<B_ * 4, 256, 0, stream>>>(qkvb, ob);
    k_gemm96<1, false, true, true, false><<<M_ROWS / 64, 256, 0, stream>>>(
        ob, a1_Wo, a1_bo, p1, tvec, p0);

    // qkv region is now free: zero XP1 borders before MLP3 writes interior
    k_zb<<<3072, 256, 0, stream>>>(XP1);

    // MLP x3 (silu); last writes padded XP1[b][e][16][16]
    k_gemm96<1, true, false, false, false><<<M_ROWS / 64, 256, 0, stream>>>(
        p0, Wm0, bm0, nullptr, nullptr, p1);
    k_gemm96<1, true, false, false, false><<<M_ROWS / 64, 256, 0, stream>>>(
        p1, Wm1, bm1, nullptr, nullptr, p0);
    k_gemm96<1, true, false, false, true><<<M_ROWS / 64, 256, 0, stream>>>(
        p0, Wm2, bm2, nullptr, nullptr, XP1);

    // decoder (channel-group split convs)
    k_convg<96, 14, 48, 8><<<2 * 6 * 98, 256, 0, stream>>>(XP1, Wr, bd1, C1);
    k_ln_pad<28><<<B_ * 48, 256, 0, stream>>>(C1, l1g, l1b, XP2);
    k_convg<48, 28, 24, 8><<<2 * 3 * 392, 256, 0, stream>>>(XP2, Wr + 73728, bd2, C2);
    k_ln_pad<56><<<B_ * 24, 256, 0, stream>>>(C2, l2g, l2b, XP3);
    k_convg<24, 56, 12, 12><<<2 * 1 * 1568, 256, 0, stream>>>(XP3, Wr + 92160, bd3, C3);
    k_ln_spatial<12544><<<B_ * 12, 256, 0, stream>>>(C3, l3g, l3b);
    k_conv_final<<<2 * 6272, 256, 0, stream>>>(C3, Wr + 96768, bd4, out);
}

// Round 4
// 848.954 us; speedup vs baseline: 1.6045x; 1.0994x over previous
//
#include <hip/hip_runtime.h>
#include <cmath>

// ---------------------------------------------------------------------------
// TimestepVisionTransformer — fp32. Round 3: scalar-broadcast attention
// (one thread = one query; K/V rows via s_load, no LDS).
// B=128, IMG=224, P=16, C_IN=1, E=96, H=4, d=24, NAX=14, N=196, M=B*N=25088
// ---------------------------------------------------------------------------

#define B_   128
#define NPATCH 196
#define M_ROWS (B_*NPATCH)     // 25088
#define E_   96

// ---------------------------------------------------------------------------
// time embedding: 1 block x 128 threads
// ---------------------------------------------------------------------------
__global__ void k_time(const float* __restrict__ ts,
                       const float* __restrict__ Wt1, const float* __restrict__ bt1,
                       const float* __restrict__ Wt2, const float* __restrict__ bt2,
                       float* __restrict__ timev)
{
    __shared__ float h[128];
    float e = 0.69314718055994530942f * ts[0];
    float sv = sinf(e), cv = cosf(e);
    int t = threadIdx.x;
    float z = sv * Wt1[t] + cv * Wt1[128 + t] + bt1[t];
    h[t] = z / (1.f + expf(-z));
    __syncthreads();
    if (t < 96) {
        float acc = bt2[t];
        for (int j = 0; j < 128; ++j) acc += h[j] * Wt2[j * 96 + t];
        timev[t] = acc;
    }
}

// ---------------------------------------------------------------------------
// weight repack for all 4 convT layers into per-parity float4 taps.
// Wr[par][ci][o][4] with taps {w[3-ry][3-rx], w[3-ry][1-rx], w[1-ry][3-rx], w[1-ry][1-rx]}
// layer offsets (floats): L1=0 (73728), L2=73728 (18432), L3=92160 (4608), L4=96768 (192)
// ---------------------------------------------------------------------------
__global__ void __launch_bounds__(256) k_repack(const float* __restrict__ w1,
                                                const float* __restrict__ w2,
                                                const float* __restrict__ w3,
                                                const float* __restrict__ w4f,
                                                float* __restrict__ wr)
{
    int i = blockIdx.x * 256 + threadIdx.x;
    const float* src; int CIN, COUT, e; float* dst;
    if      (i < 73728) { src = w1;  CIN = 96; COUT = 48; e = i;          dst = wr; }
    else if (i < 92160) { src = w2;  CIN = 48; COUT = 24; e = i - 73728;  dst = wr + 73728; }
    else if (i < 96768) { src = w3;  CIN = 24; COUT = 12; e = i - 92160;  dst = wr + 92160; }
    else if (i < 96960) { src = w4f; CIN = 12; COUT = 1;  e = i - 96768;  dst = wr + 96768; }
    else return;
    int per = CIN * COUT * 4;
    int par = e / per, rem = e % per;
    int ci = rem / (COUT * 4);
    int o  = (rem >> 2) % COUT;
    int j  = rem & 3;
    int ry = par >> 1, rx = par & 1;
    int wy = (j < 2)  ? (3 - ry) : (1 - ry);
    int wx = (j & 1)  ? (1 - rx) : (3 - rx);
    dst[e] = src[(ci * COUT + o) * 16 + wy * 4 + wx];
}

// ---------------------------------------------------------------------------
// zero the borders of XP1 [128*96 planes][16][16] (interior written by MLP3)
// ---------------------------------------------------------------------------
__global__ void __launch_bounds__(256) k_zb(float* __restrict__ xp)
{
    int idx = blockIdx.x * 256 + threadIdx.x;   // plane*64 + j
    int plane = idx >> 6, j = idx & 63;
    if (plane >= 12288 || j >= 60) return;
    int py, px;
    if      (j < 16) { py = 0;      px = j; }
    else if (j < 32) { py = 15;     px = j - 16; }
    else if (j < 46) { py = j - 31; px = 0; }
    else             { py = j - 45; px = 15; }
    xp[(size_t)plane * 256 + py * 16 + px] = 0.f;
}

// ---------------------------------------------------------------------------
// patch embed GEMM  [25088 x 256] @ WpT[256 x 96]  + bias + RoPE epilogue
// ---------------------------------------------------------------------------
__global__ void __launch_bounds__(256) k_patch(const float* __restrict__ x,
                                               const float* __restrict__ Wp,
                                               const float* __restrict__ bp,
                                               float* __restrict__ out)
{
    __shared__ float As[64][65];
    __shared__ float Ws[64][97];
    int t = threadIdx.x;
    int p0 = blockIdx.x * 64;
    int rg = t >> 4, cg = t & 15;
    float acc[4][6] = {};

    for (int kc = 0; kc < 4; ++kc) {
        __syncthreads();
        for (int idx = t; idx < 64 * 64; idx += 256) {
            int p = idx >> 6, kl = idx & 63;
            int patch = p0 + p;
            int b = patch / NPATCH, n = patch % NPATCH;
            int ny = n / 14, nx = n % 14;
            int py = kc * 4 + (kl >> 4), px = kl & 15;
            As[p][kl] = x[((size_t)b * 224 + ny * 16 + py) * 224 + nx * 16 + px];
        }
        for (int idx = t; idx < 64 * 96; idx += 256) {
            int e = idx >> 6, kl = idx & 63;
            Ws[kl][e] = Wp[e * 256 + kc * 64 + kl];
        }
        __syncthreads();
        for (int kk = 0; kk < 64; ++kk) {
            float a0 = As[rg * 4 + 0][kk];
            float a1 = As[rg * 4 + 1][kk];
            float a2 = As[rg * 4 + 2][kk];
            float a3 = As[rg * 4 + 3][kk];
            const float* wrow = &Ws[kk][cg * 6];
            #pragma unroll
            for (int j = 0; j < 6; ++j) {
                float wv = wrow[j];
                acc[0][j] += a0 * wv; acc[1][j] += a1 * wv;
                acc[2][j] += a2 * wv; acc[3][j] += a3 * wv;
            }
        }
    }
    #pragma unroll
    for (int i = 0; i < 4; ++i) {
        int patch = p0 + rg * 4 + i;
        int n = patch % NPATCH;
        int ny = n / 14, nx = n % 14;
        float yx = (float)(ny + nx);
        #pragma unroll
        for (int j = 0; j < 3; ++j) {
            int e0 = cg * 6 + 2 * j;
            float xe = acc[i][2 * j]     + bp[e0];
            float ye = acc[i][2 * j + 1] + bp[e0 + 1];
            float fi = (float)(e0 >> 1);
            float theta = expf(fi * (-2.f / 96.f) * 9.210340371976184f);
            float ang = theta * yx;
            float c = cosf(ang), s = sinf(ang);
            out[(size_t)patch * 96 + e0]     = xe * c - ye * s;
            out[(size_t)patch * 96 + e0 + 1] = xe * s + ye * c;
        }
    }
}

// ---------------------------------------------------------------------------
// row LayerNorm over 96, wave per row
// ---------------------------------------------------------------------------
__global__ void __launch_bounds__(256) k_ln_row(const float* __restrict__ x,
                                                const float* __restrict__ g,
                                                const float* __restrict__ bv,
                                                float* __restrict__ out, int M)
{
    int lane = threadIdx.x & 63;
    int gw = (blockIdx.x * 256 + threadIdx.x) >> 6;
    int nw = (gridDim.x * 256) >> 6;
    float g0 = g[lane], b0 = bv[lane];
    float g1 = 0.f, b1 = 0.f;
    if (lane < 32) { g1 = g[64 + lane]; b1 = bv[64 + lane]; }
    for (int r = gw; r < M; r += nw) {
        const float* xr = x + (size_t)r * 96;
        float a = xr[lane];
        float c = (lane < 32) ? xr[64 + lane] : 0.f;
        float s = a + c, q = a * a + c * c;
        #pragma unroll
        for (int off = 32; off; off >>= 1) {
            s += __shfl_xor(s, off);
            q += __shfl_xor(q, off);
        }
        float mu = s * (1.f / 96.f);
        float rstd = rsqrtf(q * (1.f / 96.f) - mu * mu + 1e-5f);
        float* orow = out + (size_t)r * 96;
        orow[lane] = (a - mu) * rstd * g0 + b0;
        if (lane < 32) orow[64 + lane] = (c - mu) * rstd * g1 + b1;
    }
}

// ---------------------------------------------------------------------------
// generic row GEMM: A[M,96] @ W[96, NCHUNKS*96] + bias, epilogues
// PADW: write into padded conv-input layout XP1[b][col][16][16] interior
// ---------------------------------------------------------------------------
template<int NCHUNKS, bool SILU, bool RES, bool ADDTIME, bool PADW>
__global__ void __launch_bounds__(256) k_gemm96(const float* __restrict__ A,
                                                const float* __restrict__ W,
                                                const float* __restrict__ bias,
                                                const float* __restrict__ res,
                                                const float* __restrict__ timev,
                                                float* __restrict__ out)
{
    __shared__ float As[64][97];
    __shared__ float Ws[96 * 96];
    constexpr int NTOT = NCHUNKS * 96;
    int t = threadIdx.x;
    size_t row0 = (size_t)blockIdx.x * 64;
    for (int idx = t; idx < 64 * 96; idx += 256)
        As[idx / 96][idx % 96] = A[row0 * 96 + idx];
    int rg = t >> 4, cg = t & 15;
    for (int ch = 0; ch < NCHUNKS; ++ch) {
        __syncthreads();
        for (int idx = t; idx < 96 * 96; idx += 256) {
            int k = idx / 96, c = idx % 96;
            Ws[idx] = W[k * NTOT + ch * 96 + c];
        }
        __syncthreads();
        float acc[4][6] = {};
        for (int kk = 0; kk < 96; ++kk) {
            float a0 = As[rg * 4 + 0][kk];
            float a1 = As[rg * 4 + 1][kk];
            float a2 = As[rg * 4 + 2][kk];
            float a3 = As[rg * 4 + 3][kk];
            const float* wrow = &Ws[kk * 96 + cg * 6];
            #pragma unroll
            for (int j = 0; j < 6; ++j) {
                float wv = wrow[j];
                acc[0][j] += a0 * wv; acc[1][j] += a1 * wv;
                acc[2][j] += a2 * wv; acc[3][j] += a3 * wv;
            }
        }
        #pragma unroll
        for (int i = 0; i < 4; ++i) {
            size_t row = row0 + rg * 4 + i;
            #pragma unroll
            for (int j = 0; j < 6; ++j) {
                int lc = cg * 6 + j;
                int col = ch * 96 + lc;
                float v = acc[i][j] + bias[col];
                if constexpr (RES)     v += res[row * 96 + lc];
                if constexpr (ADDTIME) v += timev[lc];
                if constexpr (SILU)    v = v / (1.f + expf(-v));
                if constexpr (PADW) {
                    size_t b = row / NPATCH; int n = (int)(row % NPATCH);
                    int ny = n / 14, nx = n % 14;
                    out[(b * 96 + col) * 256 + (1 + ny) * 16 + (1 + nx)] = v;
                } else {
                    out[row * NTOT + col] = v;
                }
            }
        }
    }
}

// ---------------------------------------------------------------------------
// attention: one thread = one query row. K/V rows are wave-uniform ->
// compiler emits s_load (constant cache broadcast); no LDS, no barriers.
// Max-free softmax (scores O(0.3) for this model; clamp 60 for safety).
// grid B*H blocks x 256 threads (lanes 196..255 idle).
// ---------------------------------------------------------------------------
__global__ void __launch_bounds__(256) k_attn(const float* __restrict__ qkv,
                                              float* __restrict__ o)
{
    int bh = blockIdx.x;
    int b = bh >> 2, h = bh & 3;
    const float* base = qkv + (size_t)b * NPATCH * 288 + h * 24;
    int q = threadIdx.x;
    bool active = q < NPATCH;
    int qq = active ? q : 0;

    float qv[24], acc[24];
    const float4* qrow = (const float4*)(base + (size_t)qq * 288);
    #pragma unroll
    for (int j = 0; j < 6; ++j) {
        float4 v = qrow[j];
        qv[4 * j] = v.x; qv[4 * j + 1] = v.y; qv[4 * j + 2] = v.z; qv[4 * j + 3] = v.w;
    }
    #pragma unroll
    for (int d = 0; d < 24; ++d) acc[d] = 0.f;
    float sum = 0.f;
    const float scale = 0.2041241452319315f;   // 1/sqrt(24)

    #pragma unroll 2
    for (int k = 0; k < NPATCH; ++k) {
        const float* Kr = base + 96  + (size_t)k * 288;  // wave-uniform -> s_load
        const float* Vr = base + 192 + (size_t)k * 288;  // wave-uniform -> s_load
        float s0 = 0.f, s1 = 0.f, s2 = 0.f, s3 = 0.f;
        #pragma unroll
        for (int d = 0; d < 24; d += 4) {
            s0 += qv[d]     * Kr[d];
            s1 += qv[d + 1] * Kr[d + 1];
            s2 += qv[d + 2] * Kr[d + 2];
            s3 += qv[d + 3] * Kr[d + 3];
        }
        float s = (s0 + s1) + (s2 + s3);
        float p = __expf(fminf(s * scale, 60.f));
        sum += p;
        #pragma unroll
        for (int d = 0; d < 24; ++d) acc[d] += p * Vr[d];
    }

    if (active) {
        float inv = 1.f / sum;
        float4* orow = (float4*)(o + ((size_t)b * NPATCH + q) * 96 + h * 24);
        #pragma unroll
        for (int j = 0; j < 6; ++j) {
            float4 v;
            v.x = acc[4 * j] * inv; v.y = acc[4 * j + 1] * inv;
            v.z = acc[4 * j + 2] * inv; v.w = acc[4 * j + 3] * inv;
            orow[j] = v;
        }
    }
}

// ---------------------------------------------------------------------------
// transposed conv on zero-padded input XP[b][CIN][HIN+2][HIN+2].
// Channel-group split: one thread = (ry, og, b, pixel-pair), computing
// outputs (2py+ry, 2px..2px+1) for G channels. ry/og derived from blockIdx
// (scalar) -> weight float4 reads are s_load broadcasts. No LDS.
// grid = 2 * (COUT/G) * B*HIN*HIN/256.
// ---------------------------------------------------------------------------
template<int CIN, int HIN, int COUT, int G>
__global__ void __launch_bounds__(256) k_convg(const float* __restrict__ xp,
                                               const float* __restrict__ wr,
                                               const float* __restrict__ bias,
                                               float* __restrict__ out)
{
    constexpr int HP = HIN + 2;
    constexpr int HO = 2 * HIN;
    constexpr int NPB = (B_ * HIN * HIN) / 256;   // pixel-blocks per (ry,og)
    int pb = blockIdx.x % NPB;
    int z  = blockIdx.x / NPB;        // z = ry * (COUT/G) + og
    int og = z % (COUT / G);
    int ry = z / (COUT / G);
    int o0 = og * G;
    int rem = pb * 256 + threadIdx.x; // in [0, B*HIN*HIN)
    int b   = rem / (HIN * HIN);
    int pix = rem % (HIN * HIN);
    int py = pix / HIN, px = pix % HIN;
    const float* xb = xp + ((size_t)b * CIN) * (HP * HP) + (py + ry) * HP + px;
    const float4* w4 = (const float4*)wr;
    float acc0[G], acc1[G];
    #pragma unroll
    for (int o = 0; o < G; ++o) { acc0[o] = 0.f; acc1[o] = 0.f; }
    float f00 = xb[0], f01 = xb[1], f02 = xb[2];
    float f10 = xb[HP], f11 = xb[HP + 1], f12 = xb[HP + 2];
    for (int ci = 0; ci < CIN; ++ci) {
        int cn = (ci + 1 < CIN) ? (ci + 1) : (CIN - 1);
        const float* xn = xb + (size_t)cn * (HP * HP);
        float n00 = xn[0], n01 = xn[1], n02 = xn[2];
        float n10 = xn[HP], n11 = xn[HP + 1], n12 = xn[HP + 2];
        const float4* w0 = w4 + ((size_t)(2 * ry) * CIN + ci) * COUT + o0;
        const float4* w1 = w0 + (size_t)CIN * COUT;
        #pragma unroll
        for (int o = 0; o < G; ++o) {
            float4 W0 = w0[o], W1 = w1[o];
            acc0[o] += f00 * W0.x + f01 * W0.y + f10 * W0.z + f11 * W0.w;
            acc1[o] += f01 * W1.x + f02 * W1.y + f11 * W1.z + f12 * W1.w;
        }
        f00 = n00; f01 = n01; f02 = n02; f10 = n10; f11 = n11; f12 = n12;
    }
    int oy = 2 * py + ry;
    #pragma unroll
    for (int o = 0; o < G; ++o) {
        float bb = bias[o0 + o];
        float2 v; v.x = acc0[o] + bb; v.y = acc1[o] + bb;
        *(float2*)(out + ((size_t)(b * COUT + o0 + o) * HO + oy) * HO + 2 * px) = v;
    }
}

// ---------------------------------------------------------------------------
// spatial LN (per b,o over H*H) + per-position affine + silu, writing into
// zero-padded layout XP[plane][(H+2)][(H+2)] for the next conv.
// ---------------------------------------------------------------------------
template<int H>
__global__ void __launch_bounds__(256) k_ln_pad(const float* __restrict__ cin,
                                                const float* __restrict__ g,
                                                const float* __restrict__ bv,
                                                float* __restrict__ xp)
{
    constexpr int HW = H * H;
    constexpr int HP = H + 2;
    constexpr int HWP = HP * HP;
    size_t plane = blockIdx.x;
    const float* src = cin + plane * HW;
    float* dst = xp + plane * HWP;
    int t = threadIdx.x;
    float s = 0.f, q = 0.f;
    for (int i = t; i < HW; i += 256) {
        float v = src[i];
        s += v; q += v * v;
    }
    #pragma unroll
    for (int off = 32; off; off >>= 1) {
        s += __shfl_xor(s, off);
        q += __shfl_xor(q, off);
    }
    __shared__ float rs[8];
    int wave = t >> 6, lane = t & 63;
    if (lane == 0) { rs[wave] = s; rs[4 + wave] = q; }
    __syncthreads();
    float st = rs[0] + rs[1] + rs[2] + rs[3];
    float qt = rs[4] + rs[5] + rs[6] + rs[7];
    float mu = st / (float)HW;
    float rstd = rsqrtf(qt / (float)HW - mu * mu + 1e-5f);
    for (int i = t; i < HWP; i += 256) {
        int py = i / HP, px = i % HP;
        float v = 0.f;
        if (py >= 1 && py <= H && px >= 1 && px <= H) {
            int j = (py - 1) * H + (px - 1);
            float u = (src[j] - mu) * rstd * g[j] + bv[j];
            v = u / (1.f + expf(-u));
        }
        dst[i] = v;
    }
}

// ---------------------------------------------------------------------------
// in-place spatial LN + affine + silu (layer 3; final conv handles bounds)
// ---------------------------------------------------------------------------
template<int HW>
__global__ void __launch_bounds__(256) k_ln_spatial(float* __restrict__ f,
                                                    const float* __restrict__ g,
                                                    const float* __restrict__ bv)
{
    size_t base = (size_t)blockIdx.x * HW;
    int t = threadIdx.x;
    float s = 0.f, q = 0.f;
    for (int i = t; i < HW; i += 256) {
        float v = f[base + i];
        s += v; q += v * v;
    }
    #pragma unroll
    for (int off = 32; off; off >>= 1) {
        s += __shfl_xor(s, off);
        q += __shfl_xor(q, off);
    }
    __shared__ float rs[8];
    int wave = t >> 6, lane = t & 63;
    if (lane == 0) { rs[wave] = s; rs[4 + wave] = q; }
    __syncthreads();
    float st = rs[0] + rs[1] + rs[2] + rs[3];
    float qt = rs[4] + rs[5] + rs[6] + rs[7];
    float mu = st / (float)HW;
    float rstd = rsqrtf(qt / (float)HW - mu * mu + 1e-5f);
    for (int i = t; i < HW; i += 256) {
        float v = (f[base + i] - mu) * rstd * g[i] + bv[i];
        f[base + i] = v / (1.f + expf(-v));
    }
}

// ---------------------------------------------------------------------------
// final convT 12->1 on compact input with boundary masks + silu + clip
// ---------------------------------------------------------------------------
__global__ void __launch_bounds__(256) k_conv_final(const float* __restrict__ x,
                                                    const float* __restrict__ wr,
                                                    const float* __restrict__ bias,
                                                    float* __restrict__ out)
{
    constexpr int HIN = 112, CIN = 12, HP2 = 12544;
    constexpr int NPB = (B_ * HIN * HIN) / 256;   // 6272
    int pb = blockIdx.x % NPB;
    int ry = blockIdx.x / NPB;
    int rem = pb * 256 + threadIdx.x;
    int b   = rem / (HIN * HIN);
    int pix = rem % (HIN * HIN);
    int py = pix / HIN, px = pix % HIN;
    int r0 = py + ry - 1, r1 = r0 + 1;
    bool my0 = r0 >= 0, my1 = r1 < HIN;
    bool mx0 = px >= 1, mx2 = px + 1 < HIN;
    const float* xb = x + (size_t)b * CIN * HP2;
    const float4* w4 = (const float4*)wr;
    float acc0 = 0.f, acc1 = 0.f;
    #pragma unroll
    for (int ci = 0; ci < CIN; ++ci) {
        const float* xc = xb + ci * HP2;
        const float* xr0 = xc + r0 * HIN + px;
        const float* xr1 = xc + r1 * HIN + px;
        float g00 = (my0 && mx0) ? xr0[-1] : 0.f;
        float g01 = my0 ? xr0[0] : 0.f;
        float g02 = (my0 && mx2) ? xr0[1] : 0.f;
        float g10 = (my1 && mx0) ? xr1[-1] : 0.f;
        float g11 = my1 ? xr1[0] : 0.f;
        float g12 = (my1 && mx2) ? xr1[1] : 0.f;
        float4 W0 = w4[(2 * ry) * CIN + ci];
        float4 W1 = w4[(2 * ry + 1) * CIN + ci];
        acc0 += g00 * W0.x + g01 * W0.y + g10 * W0.z + g11 * W0.w;
        acc1 += g01 * W1.x + g02 * W1.y + g11 * W1.z + g12 * W1.w;
    }
    float bb = bias[0];
    float u0 = acc0 + bb, u1 = acc1 + bb;
    u0 = u0 / (1.f + expf(-u0));
    u1 = u1 / (1.f + expf(-u1));
    float2 v;
    v.x = fminf(fmaxf(u0, 0.f), 1.f);
    v.y = fminf(fmaxf(u1, 0.f), 1.f);
    int oy = 2 * py + ry;
    *(float2*)(out + (size_t)b * 50176 + oy * 224 + 2 * px) = v;
}

// ---------------------------------------------------------------------------
// launch
// ---------------------------------------------------------------------------
extern "C" void kernel_launch(void* const* d_in, const int* in_sizes, int n_in,
                              void* d_out, int out_size, void* d_ws, size_t ws_size,
                              hipStream_t stream)
{
    const float* x       = (const float*)d_in[0];
    const float* ts      = (const float*)d_in[1];
    const float* Wp      = (const float*)d_in[2];
    const float* bp      = (const float*)d_in[3];
    const float* Wt1     = (const float*)d_in[4];
    const float* bt1     = (const float*)d_in[5];
    const float* Wt2     = (const float*)d_in[6];
    const float* bt2     = (const float*)d_in[7];
    const float* a0_g    = (const float*)d_in[8];
    const float* a0_b    = (const float*)d_in[9];
    const float* a0_Wqkv = (const float*)d_in[10];
    const float* a0_bqkv = (const float*)d_in[11];
    const float* a0_Wo   = (const float*)d_in[12];
    const float* a0_bo   = (const float*)d_in[13];
    const float* a1_g    = (const float*)d_in[14];
    const float* a1_b    = (const float*)d_in[15];
    const float* a1_Wqkv = (const float*)d_in[16];
    const float* a1_bqkv = (const float*)d_in[17];
    const float* a1_Wo   = (const float*)d_in[18];
    const float* a1_bo   = (const float*)d_in[19];
    const float* Wm0     = (const float*)d_in[20];
    const float* bm0     = (const float*)d_in[21];
    const float* Wm1     = (const float*)d_in[22];
    const float* bm1     = (const float*)d_in[23];
    const float* Wm2     = (const float*)d_in[24];
    const float* bm2     = (const float*)d_in[25];
    const float* Wd1     = (const float*)d_in[26];
    const float* bd1     = (const float*)d_in[27];
    const float* l1g     = (const float*)d_in[28];
    const float* l1b     = (const float*)d_in[29];
    const float* Wd2     = (const float*)d_in[30];
    const float* bd2     = (const float*)d_in[31];
    const float* l2g     = (const float*)d_in[32];
    const float* l2b     = (const float*)d_in[33];
    const float* Wd3     = (const float*)d_in[34];
    const float* bd3     = (const float*)d_in[35];
    const float* l3g     = (const float*)d_in[36];
    const float* l3b     = (const float*)d_in[37];
    const float* Wd4     = (const float*)d_in[38];
    const float* bd4     = (const float*)d_in[39];
    float* out = (float*)d_out;

    // arena (floats); R = 25088*96
    const size_t R = 2408448;
    float* ws   = (float*)d_ws;
    float* tvec = ws;                          // 96
    float* p0   = ws + 512;                    // R
    float* h    = ws + 512 + R;                // R
    float* qkvb = ws + 512 + 2 * R;            // 3R
    float* ob   = ws + 512 + 5 * R;            // R
    float* p1   = ws + 512 + 6 * R;            // R
    // decoder aliases:
    float* XP1  = ws + 512 + 2 * R;            // 3,145,728  (qkv region)
    float* C1   = ws + 512 + 5 * R;            // 4,816,896  (ob+p1 regions)
    float* XP2  = ws + 512 + 7 * R;            // 5,529,600
    float* C2   = ws + 512;                    // 9,633,792  (p0..qkv regions)
    float* XP3  = ws + 512 + 7 * R + 5529600;  // 10,334,208
    float* C3   = ws + 512;                    // 19,267,584 (p0..XP2 regions)
    float* Wr   = ws + 512 + 7 * R + 5529600 + 10334208;  // 96,960
    const size_t NEED = (512 + 7 * R + 5529600 + 10334208 + 96960) * sizeof(float); // ~131.3 MB
    if (ws_size < NEED) return;

    k_time<<<1, 128, 0, stream>>>(ts, Wt1, bt1, Wt2, bt2, tvec);
    k_repack<<<379, 256, 0, stream>>>(Wd1, Wd2, Wd3, Wd4, Wr);
    k_patch<<<M_ROWS / 64, 256, 0, stream>>>(x, Wp, bp, p0);

    // MHSA block 0
    k_ln_row<<<1024, 256, 0, stream>>>(p0, a0_g, a0_b, h, M_ROWS);
    k_gemm96<3, false, false, false, false><<<M_ROWS / 64, 256, 0, stream>>>(
        h, a0_Wqkv, a0_bqkv, nullptr, nullptr, qkvb);
    k_attn<<<B_ * 4, 256, 0, stream>>>(qkvb, ob);
    k_gemm96<1, false, true, false, false><<<M_ROWS / 64, 256, 0, stream>>>(
        ob, a0_Wo, a0_bo, p0, nullptr, p1);

    // MHSA block 1 (+time in epilogue)
    k_ln_row<<<1024, 256, 0, stream>>>(p1, a1_g, a1_b, h, M_ROWS);
    k_gemm96<3, false, false, false, false><<<M_ROWS / 64, 256, 0, stream>>>(
        h, a1_Wqkv, a1_bqkv, nullptr, nullptr, qkvb);
    k_attn<<<B_ * 4, 256, 0, stream>>>(qkvb, ob);
    k_gemm96<1, false, true, true, false><<<M_ROWS / 64, 256, 0, stream>>>(
        ob, a1_Wo, a1_bo, p1, tvec, p0);

    // qkv region is now free: zero XP1 borders before MLP3 writes interior
    k_zb<<<3072, 256, 0, stream>>>(XP1);

    // MLP x3 (silu); last writes padded XP1[b][e][16][16]
    k_gemm96<1, true, false, false, false><<<M_ROWS / 64, 256, 0, stream>>>(
        p0, Wm0, bm0, nullptr, nullptr, p1);
    k_gemm96<1, true, false, false, false><<<M_ROWS / 64, 256, 0, stream>>>(
        p1, Wm1, bm1, nullptr, nullptr, p0);
    k_gemm96<1, true, false, false, true><<<M_ROWS / 64, 256, 0, stream>>>(
        p0, Wm2, bm2, nullptr, nullptr, XP1);

    // decoder (channel-group split convs)
    k_convg<96, 14, 48, 8><<<2 * 6 * 98, 256, 0, stream>>>(XP1, Wr, bd1, C1);
    k_ln_pad<28><<<B_ * 48, 256, 0, stream>>>(C1, l1g, l1b, XP2);
    k_convg<48, 28, 24, 8><<<2 * 3 * 392, 256, 0, stream>>>(XP2, Wr + 73728, bd2, C2);
    k_ln_pad<56><<<B_ * 24, 256, 0, stream>>>(C2, l2g, l2b, XP3);
    k_convg<24, 56, 12, 12><<<2 * 1 * 1568, 256, 0, stream>>>(XP3, Wr + 92160, bd3, C3);
    k_ln_spatial<12544><<<B_ * 12, 256, 0, stream>>>(C3, l3g, l3b);
    k_conv_final<<<2 * 6272, 256, 0, stream>>>(C3, Wr + 96768, bd4, out);
}

// Round 5
// 846.968 us; speedup vs baseline: 1.6083x; 1.0023x over previous
//
#include <hip/hip_runtime.h>
#include <cmath>

// ---------------------------------------------------------------------------
// TimestepVisionTransformer — fp32. Round 4: K-split attention
// (4 key-segments per (b,h); LDS-broadcast K/V; linear partial combine).
// B=128, IMG=224, P=16, C_IN=1, E=96, H=4, d=24, NAX=14, N=196, M=B*N=25088
// ---------------------------------------------------------------------------

#define B_   128
#define NPATCH 196
#define M_ROWS (B_*NPATCH)     // 25088
#define E_   96
#define KS   4
#define SEG  49

// ---------------------------------------------------------------------------
// time embedding: 1 block x 128 threads
// ---------------------------------------------------------------------------
__global__ void k_time(const float* __restrict__ ts,
                       const float* __restrict__ Wt1, const float* __restrict__ bt1,
                       const float* __restrict__ Wt2, const float* __restrict__ bt2,
                       float* __restrict__ timev)
{
    __shared__ float h[128];
    float e = 0.69314718055994530942f * ts[0];
    float sv = sinf(e), cv = cosf(e);
    int t = threadIdx.x;
    float z = sv * Wt1[t] + cv * Wt1[128 + t] + bt1[t];
    h[t] = z / (1.f + expf(-z));
    __syncthreads();
    if (t < 96) {
        float acc = bt2[t];
        for (int j = 0; j < 128; ++j) acc += h[j] * Wt2[j * 96 + t];
        timev[t] = acc;
    }
}

// ---------------------------------------------------------------------------
// weight repack for all 4 convT layers into per-parity float4 taps.
// ---------------------------------------------------------------------------
__global__ void __launch_bounds__(256) k_repack(const float* __restrict__ w1,
                                                const float* __restrict__ w2,
                                                const float* __restrict__ w3,
                                                const float* __restrict__ w4f,
                                                float* __restrict__ wr)
{
    int i = blockIdx.x * 256 + threadIdx.x;
    const float* src; int CIN, COUT, e; float* dst;
    if      (i < 73728) { src = w1;  CIN = 96; COUT = 48; e = i;          dst = wr; }
    else if (i < 92160) { src = w2;  CIN = 48; COUT = 24; e = i - 73728;  dst = wr + 73728; }
    else if (i < 96768) { src = w3;  CIN = 24; COUT = 12; e = i - 92160;  dst = wr + 92160; }
    else if (i < 96960) { src = w4f; CIN = 12; COUT = 1;  e = i - 96768;  dst = wr + 96768; }
    else return;
    int per = CIN * COUT * 4;
    int par = e / per, rem = e % per;
    int ci = rem / (COUT * 4);
    int o  = (rem >> 2) % COUT;
    int j  = rem & 3;
    int ry = par >> 1, rx = par & 1;
    int wy = (j < 2)  ? (3 - ry) : (1 - ry);
    int wx = (j & 1)  ? (1 - rx) : (3 - rx);
    dst[e] = src[(ci * COUT + o) * 16 + wy * 4 + wx];
}

// ---------------------------------------------------------------------------
// zero the borders of XP1 [128*96 planes][16][16] (interior written by MLP3)
// ---------------------------------------------------------------------------
__global__ void __launch_bounds__(256) k_zb(float* __restrict__ xp)
{
    int idx = blockIdx.x * 256 + threadIdx.x;   // plane*64 + j
    int plane = idx >> 6, j = idx & 63;
    if (plane >= 12288 || j >= 60) return;
    int py, px;
    if      (j < 16) { py = 0;      px = j; }
    else if (j < 32) { py = 15;     px = j - 16; }
    else if (j < 46) { py = j - 31; px = 0; }
    else             { py = j - 45; px = 15; }
    xp[(size_t)plane * 256 + py * 16 + px] = 0.f;
}

// ---------------------------------------------------------------------------
// patch embed GEMM  [25088 x 256] @ WpT[256 x 96]  + bias + RoPE epilogue
// ---------------------------------------------------------------------------
__global__ void __launch_bounds__(256) k_patch(const float* __restrict__ x,
                                               const float* __restrict__ Wp,
                                               const float* __restrict__ bp,
                                               float* __restrict__ out)
{
    __shared__ float As[64][65];
    __shared__ float Ws[64][97];
    int t = threadIdx.x;
    int p0 = blockIdx.x * 64;
    int rg = t >> 4, cg = t & 15;
    float acc[4][6] = {};

    for (int kc = 0; kc < 4; ++kc) {
        __syncthreads();
        for (int idx = t; idx < 64 * 64; idx += 256) {
            int p = idx >> 6, kl = idx & 63;
            int patch = p0 + p;
            int b = patch / NPATCH, n = patch % NPATCH;
            int ny = n / 14, nx = n % 14;
            int py = kc * 4 + (kl >> 4), px = kl & 15;
            As[p][kl] = x[((size_t)b * 224 + ny * 16 + py) * 224 + nx * 16 + px];
        }
        for (int idx = t; idx < 64 * 96; idx += 256) {
            int e = idx >> 6, kl = idx & 63;
            Ws[kl][e] = Wp[e * 256 + kc * 64 + kl];
        }
        __syncthreads();
        for (int kk = 0; kk < 64; ++kk) {
            float a0 = As[rg * 4 + 0][kk];
            float a1 = As[rg * 4 + 1][kk];
            float a2 = As[rg * 4 + 2][kk];
            float a3 = As[rg * 4 + 3][kk];
            const float* wrow = &Ws[kk][cg * 6];
            #pragma unroll
            for (int j = 0; j < 6; ++j) {
                float wv = wrow[j];
                acc[0][j] += a0 * wv; acc[1][j] += a1 * wv;
                acc[2][j] += a2 * wv; acc[3][j] += a3 * wv;
            }
        }
    }
    #pragma unroll
    for (int i = 0; i < 4; ++i) {
        int patch = p0 + rg * 4 + i;
        int n = patch % NPATCH;
        int ny = n / 14, nx = n % 14;
        float yx = (float)(ny + nx);
        #pragma unroll
        for (int j = 0; j < 3; ++j) {
            int e0 = cg * 6 + 2 * j;
            float xe = acc[i][2 * j]     + bp[e0];
            float ye = acc[i][2 * j + 1] + bp[e0 + 1];
            float fi = (float)(e0 >> 1);
            float theta = expf(fi * (-2.f / 96.f) * 9.210340371976184f);
            float ang = theta * yx;
            float c = cosf(ang), s = sinf(ang);
            out[(size_t)patch * 96 + e0]     = xe * c - ye * s;
            out[(size_t)patch * 96 + e0 + 1] = xe * s + ye * c;
        }
    }
}

// ---------------------------------------------------------------------------
// row LayerNorm over 96, wave per row
// ---------------------------------------------------------------------------
__global__ void __launch_bounds__(256) k_ln_row(const float* __restrict__ x,
                                                const float* __restrict__ g,
                                                const float* __restrict__ bv,
                                                float* __restrict__ out, int M)
{
    int lane = threadIdx.x & 63;
    int gw = (blockIdx.x * 256 + threadIdx.x) >> 6;
    int nw = (gridDim.x * 256) >> 6;
    float g0 = g[lane], b0 = bv[lane];
    float g1 = 0.f, b1 = 0.f;
    if (lane < 32) { g1 = g[64 + lane]; b1 = bv[64 + lane]; }
    for (int r = gw; r < M; r += nw) {
        const float* xr = x + (size_t)r * 96;
        float a = xr[lane];
        float c = (lane < 32) ? xr[64 + lane] : 0.f;
        float s = a + c, q = a * a + c * c;
        #pragma unroll
        for (int off = 32; off; off >>= 1) {
            s += __shfl_xor(s, off);
            q += __shfl_xor(q, off);
        }
        float mu = s * (1.f / 96.f);
        float rstd = rsqrtf(q * (1.f / 96.f) - mu * mu + 1e-5f);
        float* orow = out + (size_t)r * 96;
        orow[lane] = (a - mu) * rstd * g0 + b0;
        if (lane < 32) orow[64 + lane] = (c - mu) * rstd * g1 + b1;
    }
}

// ---------------------------------------------------------------------------
// generic row GEMM: A[M,96] @ W[96, NCHUNKS*96] + bias, epilogues
// PADW: write into padded conv-input layout XP1[b][col][16][16] interior
// ---------------------------------------------------------------------------
template<int NCHUNKS, bool SILU, bool RES, bool ADDTIME, bool PADW>
__global__ void __launch_bounds__(256) k_gemm96(const float* __restrict__ A,
                                                const float* __restrict__ W,
                                                const float* __restrict__ bias,
                                                const float* __restrict__ res,
                                                const float* __restrict__ timev,
                                                float* __restrict__ out)
{
    __shared__ float As[64][97];
    __shared__ float Ws[96 * 96];
    constexpr int NTOT = NCHUNKS * 96;
    int t = threadIdx.x;
    size_t row0 = (size_t)blockIdx.x * 64;
    for (int idx = t; idx < 64 * 96; idx += 256)
        As[idx / 96][idx % 96] = A[row0 * 96 + idx];
    int rg = t >> 4, cg = t & 15;
    for (int ch = 0; ch < NCHUNKS; ++ch) {
        __syncthreads();
        for (int idx = t; idx < 96 * 96; idx += 256) {
            int k = idx / 96, c = idx % 96;
            Ws[idx] = W[k * NTOT + ch * 96 + c];
        }
        __syncthreads();
        float acc[4][6] = {};
        for (int kk = 0; kk < 96; ++kk) {
            float a0 = As[rg * 4 + 0][kk];
            float a1 = As[rg * 4 + 1][kk];
            float a2 = As[rg * 4 + 2][kk];
            float a3 = As[rg * 4 + 3][kk];
            const float* wrow = &Ws[kk * 96 + cg * 6];
            #pragma unroll
            for (int j = 0; j < 6; ++j) {
                float wv = wrow[j];
                acc[0][j] += a0 * wv; acc[1][j] += a1 * wv;
                acc[2][j] += a2 * wv; acc[3][j] += a3 * wv;
            }
        }
        #pragma unroll
        for (int i = 0; i < 4; ++i) {
            size_t row = row0 + rg * 4 + i;
            #pragma unroll
            for (int j = 0; j < 6; ++j) {
                int lc = cg * 6 + j;
                int col = ch * 96 + lc;
                float v = acc[i][j] + bias[col];
                if constexpr (RES)     v += res[row * 96 + lc];
                if constexpr (ADDTIME) v += timev[lc];
                if constexpr (SILU)    v = v / (1.f + expf(-v));
                if constexpr (PADW) {
                    size_t b = row / NPATCH; int n = (int)(row % NPATCH);
                    int ny = n / 14, nx = n % 14;
                    out[(b * 96 + col) * 256 + (1 + ny) * 16 + (1 + nx)] = v;
                } else {
                    out[row * NTOT + col] = v;
                }
            }
        }
    }
}

// ---------------------------------------------------------------------------
// attention partials: block = (b,h,seg). Stage 49 K/V rows in LDS; one
// thread = one query; uniform-address ds_read -> broadcast. Max-free
// softmax partials (sum, acc[24]) are linear -> combine later.
// grid B*H*KS blocks x 256 threads.
// ---------------------------------------------------------------------------
__global__ void __launch_bounds__(256) k_attn_part(const float* __restrict__ qkv,
                                                   float* __restrict__ part)
{
    int blk = blockIdx.x;          // bh*KS + seg
    int seg = blk % KS;
    int bh  = blk / KS;
    int b = bh >> 2, h = bh & 3;
    const float* base = qkv + (size_t)b * NPATCH * 288 + h * 24;
    __shared__ __align__(16) float KV[SEG * 48];
    int t = threadIdx.x;
    int k0 = seg * SEG;
    for (int i = t; i < SEG * 48; i += 256) {
        int k = i / 48, j = i % 48;
        KV[i] = base[(size_t)(k0 + k) * 288 + 96 + (j < 24 ? j : j + 72)];
    }
    __syncthreads();

    int q = (t < NPATCH) ? t : 0;
    float qv[24], acc[24];
    const float4* qrow = (const float4*)(base + (size_t)q * 288);
    #pragma unroll
    for (int j = 0; j < 6; ++j) {
        float4 v = qrow[j];
        qv[4 * j] = v.x; qv[4 * j + 1] = v.y; qv[4 * j + 2] = v.z; qv[4 * j + 3] = v.w;
    }
    #pragma unroll
    for (int d = 0; d < 24; ++d) acc[d] = 0.f;
    float sum = 0.f;
    const float scale = 0.2041241452319315f;   // 1/sqrt(24)

    #pragma unroll 2
    for (int k = 0; k < SEG; ++k) {
        const float4* kr = (const float4*)(&KV[k * 48]);   // uniform addr
        float s0 = 0.f, s1 = 0.f, s2 = 0.f, s3 = 0.f;
        #pragma unroll
        for (int j = 0; j < 6; ++j) {
            float4 Kv = kr[j];
            s0 += qv[4 * j]     * Kv.x;
            s1 += qv[4 * j + 1] * Kv.y;
            s2 += qv[4 * j + 2] * Kv.z;
            s3 += qv[4 * j + 3] * Kv.w;
        }
        float s = (s0 + s1) + (s2 + s3);
        float p = __expf(fminf(s * scale, 60.f));
        sum += p;
        #pragma unroll
        for (int j = 0; j < 6; ++j) {
            float4 Vv = kr[6 + j];
            acc[4 * j]     += p * Vv.x;
            acc[4 * j + 1] += p * Vv.y;
            acc[4 * j + 2] += p * Vv.z;
            acc[4 * j + 3] += p * Vv.w;
        }
    }

    if (t < NPATCH) {
        float4* pp = (float4*)(part + ((size_t)blk * NPATCH + t) * 28);
        #pragma unroll
        for (int j = 0; j < 6; ++j) {
            float4 v;
            v.x = acc[4 * j]; v.y = acc[4 * j + 1];
            v.z = acc[4 * j + 2]; v.w = acc[4 * j + 3];
            pp[j] = v;
        }
        float4 sv; sv.x = sum; sv.y = 0.f; sv.z = 0.f; sv.w = 0.f;
        pp[6] = sv;
    }
}

// ---------------------------------------------------------------------------
// combine K-split partials: o[b][q][h*24..] = Σacc / Σsum
// grid = B*H*196/256 = 1568 blocks.
// ---------------------------------------------------------------------------
__global__ void __launch_bounds__(256) k_attn_comb(const float* __restrict__ part,
                                                   float* __restrict__ o)
{
    int idx = blockIdx.x * 256 + threadIdx.x;   // bh*196 + q
    int bh = idx / NPATCH, q = idx % NPATCH;
    int b = bh >> 2, h = bh & 3;
    float acc[24];
    #pragma unroll
    for (int d = 0; d < 24; ++d) acc[d] = 0.f;
    float sum = 0.f;
    #pragma unroll
    for (int s = 0; s < KS; ++s) {
        const float4* pp = (const float4*)(part + ((size_t)(bh * KS + s) * NPATCH + q) * 28);
        #pragma unroll
        for (int j = 0; j < 6; ++j) {
            float4 v = pp[j];
            acc[4 * j]     += v.x;
            acc[4 * j + 1] += v.y;
            acc[4 * j + 2] += v.z;
            acc[4 * j + 3] += v.w;
        }
        sum += pp[6].x;
    }
    float inv = 1.f / sum;
    float4* orow = (float4*)(o + ((size_t)b * NPATCH + q) * 96 + h * 24);
    #pragma unroll
    for (int j = 0; j < 6; ++j) {
        float4 v;
        v.x = acc[4 * j] * inv; v.y = acc[4 * j + 1] * inv;
        v.z = acc[4 * j + 2] * inv; v.w = acc[4 * j + 3] * inv;
        orow[j] = v;
    }
}

// ---------------------------------------------------------------------------
// transposed conv on zero-padded input XP[b][CIN][HIN+2][HIN+2].
// Channel-group split; weights via s_load broadcast. No LDS.
// ---------------------------------------------------------------------------
template<int CIN, int HIN, int COUT, int G>
__global__ void __launch_bounds__(256) k_convg(const float* __restrict__ xp,
                                               const float* __restrict__ wr,
                                               const float* __restrict__ bias,
                                               float* __restrict__ out)
{
    constexpr int HP = HIN + 2;
    constexpr int HO = 2 * HIN;
    constexpr int NPB = (B_ * HIN * HIN) / 256;   // pixel-blocks per (ry,og)
    int pb = blockIdx.x % NPB;
    int z  = blockIdx.x / NPB;        // z = ry * (COUT/G) + og
    int og = z % (COUT / G);
    int ry = z / (COUT / G);
    int o0 = og * G;
    int rem = pb * 256 + threadIdx.x; // in [0, B*HIN*HIN)
    int b   = rem / (HIN * HIN);
    int pix = rem % (HIN * HIN);
    int py = pix / HIN, px = pix % HIN;
    const float* xb = xp + ((size_t)b * CIN) * (HP * HP) + (py + ry) * HP + px;
    const float4* w4 = (const float4*)wr;
    float acc0[G], acc1[G];
    #pragma unroll
    for (int o = 0; o < G; ++o) { acc0[o] = 0.f; acc1[o] = 0.f; }
    float f00 = xb[0], f01 = xb[1], f02 = xb[2];
    float f10 = xb[HP], f11 = xb[HP + 1], f12 = xb[HP + 2];
    for (int ci = 0; ci < CIN; ++ci) {
        int cn = (ci + 1 < CIN) ? (ci + 1) : (CIN - 1);
        const float* xn = xb + (size_t)cn * (HP * HP);
        float n00 = xn[0], n01 = xn[1], n02 = xn[2];
        float n10 = xn[HP], n11 = xn[HP + 1], n12 = xn[HP + 2];
        const float4* w0 = w4 + ((size_t)(2 * ry) * CIN + ci) * COUT + o0;
        const float4* w1 = w0 + (size_t)CIN * COUT;
        #pragma unroll
        for (int o = 0; o < G; ++o) {
            float4 W0 = w0[o], W1 = w1[o];
            acc0[o] += f00 * W0.x + f01 * W0.y + f10 * W0.z + f11 * W0.w;
            acc1[o] += f01 * W1.x + f02 * W1.y + f11 * W1.z + f12 * W1.w;
        }
        f00 = n00; f01 = n01; f02 = n02; f10 = n10; f11 = n11; f12 = n12;
    }
    int oy = 2 * py + ry;
    #pragma unroll
    for (int o = 0; o < G; ++o) {
        float bb = bias[o0 + o];
        float2 v; v.x = acc0[o] + bb; v.y = acc1[o] + bb;
        *(float2*)(out + ((size_t)(b * COUT + o0 + o) * HO + oy) * HO + 2 * px) = v;
    }
}

// ---------------------------------------------------------------------------
// spatial LN (per b,o over H*H) + per-position affine + silu, writing into
// zero-padded layout XP[plane][(H+2)][(H+2)] for the next conv.
// ---------------------------------------------------------------------------
template<int H>
__global__ void __launch_bounds__(256) k_ln_pad(const float* __restrict__ cin,
                                                const float* __restrict__ g,
                                                const float* __restrict__ bv,
                                                float* __restrict__ xp)
{
    constexpr int HW = H * H;
    constexpr int HP = H + 2;
    constexpr int HWP = HP * HP;
    size_t plane = blockIdx.x;
    const float* src = cin + plane * HW;
    float* dst = xp + plane * HWP;
    int t = threadIdx.x;
    float s = 0.f, q = 0.f;
    for (int i = t; i < HW; i += 256) {
        float v = src[i];
        s += v; q += v * v;
    }
    #pragma unroll
    for (int off = 32; off; off >>= 1) {
        s += __shfl_xor(s, off);
        q += __shfl_xor(q, off);
    }
    __shared__ float rs[8];
    int wave = t >> 6, lane = t & 63;
    if (lane == 0) { rs[wave] = s; rs[4 + wave] = q; }
    __syncthreads();
    float st = rs[0] + rs[1] + rs[2] + rs[3];
    float qt = rs[4] + rs[5] + rs[6] + rs[7];
    float mu = st / (float)HW;
    float rstd = rsqrtf(qt / (float)HW - mu * mu + 1e-5f);
    for (int i = t; i < HWP; i += 256) {
        int py = i / HP, px = i % HP;
        float v = 0.f;
        if (py >= 1 && py <= H && px >= 1 && px <= H) {
            int j = (py - 1) * H + (px - 1);
            float u = (src[j] - mu) * rstd * g[j] + bv[j];
            v = u / (1.f + expf(-u));
        }
        dst[i] = v;
    }
}

// ---------------------------------------------------------------------------
// in-place spatial LN + affine + silu (layer 3; final conv handles bounds)
// ---------------------------------------------------------------------------
template<int HW>
__global__ void __launch_bounds__(256) k_ln_spatial(float* __restrict__ f,
                                                    const float* __restrict__ g,
                                                    const float* __restrict__ bv)
{
    size_t base = (size_t)blockIdx.x * HW;
    int t = threadIdx.x;
    float s = 0.f, q = 0.f;
    for (int i = t; i < HW; i += 256) {
        float v = f[base + i];
        s += v; q += v * v;
    }
    #pragma unroll
    for (int off = 32; off; off >>= 1) {
        s += __shfl_xor(s, off);
        q += __shfl_xor(q, off);
    }
    __shared__ float rs[8];
    int wave = t >> 6, lane = t & 63;
    if (lane == 0) { rs[wave] = s; rs[4 + wave] = q; }
    __syncthreads();
    float st = rs[0] + rs[1] + rs[2] + rs[3];
    float qt = rs[4] + rs[5] + rs[6] + rs[7];
    float mu = st / (float)HW;
    float rstd = rsqrtf(qt / (float)HW - mu * mu + 1e-5f);
    for (int i = t; i < HW; i += 256) {
        float v = (f[base + i] - mu) * rstd * g[i] + bv[i];
        f[base + i] = v / (1.f + expf(-v));
    }
}

// ---------------------------------------------------------------------------
// final convT 12->1 on compact input with boundary masks + silu + clip
// ---------------------------------------------------------------------------
__global__ void __launch_bounds__(256) k_conv_final(const float* __restrict__ x,
                                                    const float* __restrict__ wr,
                                                    const float* __restrict__ bias,
                                                    float* __restrict__ out)
{
    constexpr int HIN = 112, CIN = 12, HP2 = 12544;
    constexpr int NPB = (B_ * HIN * HIN) / 256;   // 6272
    int pb = blockIdx.x % NPB;
    int ry = blockIdx.x / NPB;
    int rem = pb * 256 + threadIdx.x;
    int b   = rem / (HIN * HIN);
    int pix = rem % (HIN * HIN);
    int py = pix / HIN, px = pix % HIN;
    int r0 = py + ry - 1, r1 = r0 + 1;
    bool my0 = r0 >= 0, my1 = r1 < HIN;
    bool mx0 = px >= 1, mx2 = px + 1 < HIN;
    const float* xb = x + (size_t)b * CIN * HP2;
    const float4* w4 = (const float4*)wr;
    float acc0 = 0.f, acc1 = 0.f;
    #pragma unroll
    for (int ci = 0; ci < CIN; ++ci) {
        const float* xc = xb + ci * HP2;
        const float* xr0 = xc + r0 * HIN + px;
        const float* xr1 = xc + r1 * HIN + px;
        float g00 = (my0 && mx0) ? xr0[-1] : 0.f;
        float g01 = my0 ? xr0[0] : 0.f;
        float g02 = (my0 && mx2) ? xr0[1] : 0.f;
        float g10 = (my1 && mx0) ? xr1[-1] : 0.f;
        float g11 = my1 ? xr1[0] : 0.f;
        float g12 = (my1 && mx2) ? xr1[1] : 0.f;
        float4 W0 = w4[(2 * ry) * CIN + ci];
        float4 W1 = w4[(2 * ry + 1) * CIN + ci];
        acc0 += g00 * W0.x + g01 * W0.y + g10 * W0.z + g11 * W0.w;
        acc1 += g01 * W1.x + g02 * W1.y + g11 * W1.z + g12 * W1.w;
    }
    float bb = bias[0];
    float u0 = acc0 + bb, u1 = acc1 + bb;
    u0 = u0 / (1.f + expf(-u0));
    u1 = u1 / (1.f + expf(-u1));
    float2 v;
    v.x = fminf(fmaxf(u0, 0.f), 1.f);
    v.y = fminf(fmaxf(u1, 0.f), 1.f);
    int oy = 2 * py + ry;
    *(float2*)(out + (size_t)b * 50176 + oy * 224 + 2 * px) = v;
}

// ---------------------------------------------------------------------------
// launch
// ---------------------------------------------------------------------------
extern "C" void kernel_launch(void* const* d_in, const int* in_sizes, int n_in,
                              void* d_out, int out_size, void* d_ws, size_t ws_size,
                              hipStream_t stream)
{
    const float* x       = (const float*)d_in[0];
    const float* ts      = (const float*)d_in[1];
    const float* Wp      = (const float*)d_in[2];
    const float* bp      = (const float*)d_in[3];
    const float* Wt1     = (const float*)d_in[4];
    const float* bt1     = (const float*)d_in[5];
    const float* Wt2     = (const float*)d_in[6];
    const float* bt2     = (const float*)d_in[7];
    const float* a0_g    = (const float*)d_in[8];
    const float* a0_b    = (const float*)d_in[9];
    const float* a0_Wqkv = (const float*)d_in[10];
    const float* a0_bqkv = (const float*)d_in[11];
    const float* a0_Wo   = (const float*)d_in[12];
    const float* a0_bo   = (const float*)d_in[13];
    const float* a1_g    = (const float*)d_in[14];
    const float* a1_b    = (const float*)d_in[15];
    const float* a1_Wqkv = (const float*)d_in[16];
    const float* a1_bqkv = (const float*)d_in[17];
    const float* a1_Wo   = (const float*)d_in[18];
    const float* a1_bo   = (const float*)d_in[19];
    const float* Wm0     = (const float*)d_in[20];
    const float* bm0     = (const float*)d_in[21];
    const float* Wm1     = (const float*)d_in[22];
    const float* bm1     = (const float*)d_in[23];
    const float* Wm2     = (const float*)d_in[24];
    const float* bm2     = (const float*)d_in[25];
    const float* Wd1     = (const float*)d_in[26];
    const float* bd1     = (const float*)d_in[27];
    const float* l1g     = (const float*)d_in[28];
    const float* l1b     = (const float*)d_in[29];
    const float* Wd2     = (const float*)d_in[30];
    const float* bd2     = (const float*)d_in[31];
    const float* l2g     = (const float*)d_in[32];
    const float* l2b     = (const float*)d_in[33];
    const float* Wd3     = (const float*)d_in[34];
    const float* bd3     = (const float*)d_in[35];
    const float* l3g     = (const float*)d_in[36];
    const float* l3b     = (const float*)d_in[37];
    const float* Wd4     = (const float*)d_in[38];
    const float* bd4     = (const float*)d_in[39];
    float* out = (float*)d_out;

    // arena (floats); R = 25088*96
    const size_t R = 2408448;
    float* ws   = (float*)d_ws;
    float* tvec = ws;                          // 96
    float* p0   = ws + 512;                    // R
    float* h    = ws + 512 + R;                // R
    float* qkvb = ws + 512 + 2 * R;            // 3R
    float* ob   = ws + 512 + 5 * R;            // R
    float* p1   = ws + 512 + 6 * R;            // R
    // attention K-split partials (aliases XP2/XP3 region, free during MHSA):
    float* part = ws + 512 + 7 * R;            // 11,239,424 floats (45 MB)
    // decoder aliases:
    float* XP1  = ws + 512 + 2 * R;            // 3,145,728  (qkv region)
    float* C1   = ws + 512 + 5 * R;            // 4,816,896  (ob+p1 regions)
    float* XP2  = ws + 512 + 7 * R;            // 5,529,600
    float* C2   = ws + 512;                    // 9,633,792  (p0..qkv regions)
    float* XP3  = ws + 512 + 7 * R + 5529600;  // 10,334,208
    float* C3   = ws + 512;                    // 19,267,584 (p0..XP2 regions)
    float* Wr   = ws + 512 + 7 * R + 5529600 + 10334208;  // 96,960
    const size_t NEED = (512 + 7 * R + 5529600 + 10334208 + 96960) * sizeof(float); // ~131.3 MB
    if (ws_size < NEED) return;

    k_time<<<1, 128, 0, stream>>>(ts, Wt1, bt1, Wt2, bt2, tvec);
    k_repack<<<379, 256, 0, stream>>>(Wd1, Wd2, Wd3, Wd4, Wr);
    k_patch<<<M_ROWS / 64, 256, 0, stream>>>(x, Wp, bp, p0);

    // MHSA block 0
    k_ln_row<<<1024, 256, 0, stream>>>(p0, a0_g, a0_b, h, M_ROWS);
    k_gemm96<3, false, false, false, false><<<M_ROWS / 64, 256, 0, stream>>>(
        h, a0_Wqkv, a0_bqkv, nullptr, nullptr, qkvb);
    k_attn_part<<<B_ * 4 * KS, 256, 0, stream>>>(qkvb, part);
    k_attn_comb<<<(B_ * 4 * NPATCH) / 256, 256, 0, stream>>>(part, ob);
    k_gemm96<1, false, true, false, false><<<M_ROWS / 64, 256, 0, stream>>>(
        ob, a0_Wo, a0_bo, p0, nullptr, p1);

    // MHSA block 1 (+time in epilogue)
    k_ln_row<<<1024, 256, 0, stream>>>(p1, a1_g, a1_b, h, M_ROWS);
    k_gemm96<3, false, false, false, false><<<M_ROWS / 64, 256, 0, stream>>>(
        h, a1_Wqkv, a1_bqkv, nullptr, nullptr, qkvb);
    k_attn_part<<<B_ * 4 * KS, 256, 0, stream>>>(qkvb, part);
    k_attn_comb<<<(B_ * 4 * NPATCH) / 256, 256, 0, stream>>>(part, ob);
    k_gemm96<1, false, true, true, false><<<M_ROWS / 64, 256, 0, stream>>>(
        ob, a1_Wo, a1_bo, p1, tvec, p0);

    // qkv region is now free: zero XP1 borders before MLP3 writes interior
    k_zb<<<3072, 256, 0, stream>>>(XP1);

    // MLP x3 (silu); last writes padded XP1[b][e][16][16]
    k_gemm96<1, true, false, false, false><<<M_ROWS / 64, 256, 0, stream>>>(
        p0, Wm0, bm0, nullptr, nullptr, p1);
    k_gemm96<1, true, false, false, false><<<M_ROWS / 64, 256, 0, stream>>>(
        p1, Wm1, bm1, nullptr, nullptr, p0);
    k_gemm96<1, true, false, false, true><<<M_ROWS / 64, 256, 0, stream>>>(
        p0, Wm2, bm2, nullptr, nullptr, XP1);

    // decoder (channel-group split convs)
    k_convg<96, 14, 48, 8><<<2 * 6 * 98, 256, 0, stream>>>(XP1, Wr, bd1, C1);
    k_ln_pad<28><<<B_ * 48, 256, 0, stream>>>(C1, l1g, l1b, XP2);
    k_convg<48, 28, 24, 8><<<2 * 3 * 392, 256, 0, stream>>>(XP2, Wr + 73728, bd2, C2);
    k_ln_pad<56><<<B_ * 24, 256, 0, stream>>>(C2, l2g, l2b, XP3);
    k_convg<24, 56, 12, 12><<<2 * 1 * 1568, 256, 0, stream>>>(XP3, Wr + 92160, bd3, C3);
    k_ln_spatial<12544><<<B_ * 12, 256, 0, stream>>>(C3, l3g, l3b);
    k_conv_final<<<2 * 6272, 256, 0, stream>>>(C3, Wr + 96768, bd4, out);
}